// Round 16
// baseline (2418.522 us; speedup 1.0000x reference)
//
#include <hip/hip_runtime.h>
#include <hip/hip_bf16.h>

typedef unsigned short u16;
typedef __attribute__((ext_vector_type(8))) short bf16x8;
typedef __attribute__((ext_vector_type(4))) float f32x4;
typedef __attribute__((ext_vector_type(4))) unsigned u32x4;

static constexpr int V = 20000, H = 400, B = 16, S = 256, NSLOT = 30, T = 10, G = 3;
static constexpr int H3 = 3 * H;           // 1200
static constexpr int NB = NSLOT * B;       // 480
static constexpr int MM = T * NB;          // 4800 vocab-GEMM rows
// encoder partition (R8 protocol — best measured)
static constexpr int ENBLK = 20;
static constexpr int ESL   = 20;
static constexpr int EROWS = 64;
static constexpr int EKP   = 416;
static constexpr int ENC_BLOCKS = 2 * ENBLK;               // 40
static constexpr int DGI_TM = (MM + 63) / 64;              // 75
static constexpr int DGI_TN = (H3 + 63) / 64;              // 19
static constexpr int DGI_TILES = DGI_TM * DGI_TN;          // 1425
// decoder dgh tiles (co-launched with attention)
static constexpr int DGH_TM = (NB + 63) / 64;              // 8
static constexpr int DGH_TN = (H3 + 63) / 64;              // 19
static constexpr int DGH_TILES = DGH_TM * DGH_TN;          // 152
// per-step rowsum tiles (co-launched with cell)
static constexpr int RS_TM = (NB + 127) / 128;             // 4
static constexpr int RS_TN = (V + 127) / 128;              // 157
static constexpr int RS_TILES = RS_TM * RS_TN;             // 628
static constexpr int CELL_BLOCKS = 750;
// fused decoder LDS strides
static constexpr int HP2 = 424;
static constexpr int SCP = 260;
static constexpr int PP  = 264;
static constexpr int CXP = 404;
static constexpr int FUSED_LDS = 32*HP2*2 + 32*SCP*4 + 32*PP*2 + 32*CXP*4; // 129024
// prep_all segment sizes
static constexpr int NE = V * H;
static constexpr int NW = H3 * H;
static constexpr int NP = 2 * ENBLK * EROWS * EKP;

__device__ __forceinline__ float bf2f(u16 v) {
    union { unsigned u; float f; } x; x.u = ((unsigned)v) << 16; return x.f;
}
__device__ __forceinline__ u16 f2bf(float f) {
    union { float f; unsigned u; } x; x.f = f;
    unsigned r = x.u + 0x7fffu + ((x.u >> 16) & 1u);   // round-to-nearest-even
    return (u16)(r >> 16);
}
__device__ __forceinline__ float sigm(float v) { return 1.f / (1.f + __expf(-v)); }

// ---------------------------------------------------------------------------
// Generic GEMM (pre-loop dgh_0): C[m][n] = A.Bt^T + bias
// ---------------------------------------------------------------------------
__global__ __launch_bounds__(256) void gemm_bt(
    const u16* __restrict__ A, const u16* __restrict__ Bt,
    const float* __restrict__ bias, float* __restrict__ C,
    int M, int N, int K, int lda, int ldb, long long ldc)
{
    __shared__ u16 As[64][40];
    __shared__ u16 Bs[64][40];
    const int m0 = blockIdx.x * 64, n0 = blockIdx.y * 64;
    const int tid = threadIdx.x, wave = tid >> 6, lane = tid & 63;
    const int wm = (wave >> 1) * 32, wn = (wave & 1) * 32;
    const int srow = tid >> 2, scol = (tid & 3) * 8;
    const int fr = lane & 15, kq = lane >> 4;
    f32x4 acc[2][2];
#pragma unroll
    for (int i = 0; i < 2; ++i)
#pragma unroll
        for (int j = 0; j < 2; ++j) acc[i][j] = (f32x4){0.f, 0.f, 0.f, 0.f};

    for (int k0 = 0; k0 < K; k0 += 32) {
        {
            int gr = m0 + srow, gc = k0 + scol;
            bf16x8 v = (bf16x8){0,0,0,0,0,0,0,0};
            if (gr < M && gc + 8 <= K) v = *(const bf16x8*)(A + (long long)gr * lda + gc);
            *(bf16x8*)&As[srow][scol] = v;
        }
        {
            int gr = n0 + srow, gc = k0 + scol;
            bf16x8 v = (bf16x8){0,0,0,0,0,0,0,0};
            if (gr < N && gc + 8 <= K) v = *(const bf16x8*)(Bt + (long long)gr * ldb + gc);
            *(bf16x8*)&Bs[srow][scol] = v;
        }
        __syncthreads();
        bf16x8 af[2], bfr[2];
#pragma unroll
        for (int i = 0; i < 2; ++i) af[i]  = *(const bf16x8*)&As[wm + i * 16 + fr][kq * 8];
#pragma unroll
        for (int j = 0; j < 2; ++j) bfr[j] = *(const bf16x8*)&Bs[wn + j * 16 + fr][kq * 8];
#pragma unroll
        for (int i = 0; i < 2; ++i)
#pragma unroll
            for (int j = 0; j < 2; ++j)
                acc[i][j] = __builtin_amdgcn_mfma_f32_16x16x32_bf16(af[i], bfr[j], acc[i][j], 0, 0, 0);
        __syncthreads();
    }

#pragma unroll
    for (int i = 0; i < 2; ++i)
#pragma unroll
        for (int j = 0; j < 2; ++j) {
            int col = n0 + wn + j * 16 + fr;
            float bv = (bias != nullptr && col < N) ? bias[col] : 0.f;
#pragma unroll
            for (int r = 0; r < 4; ++r) {
                int row = m0 + wm + i * 16 + kq * 4 + r;
                if (row < M && col < N) C[(long long)row * ldc + col] = acc[i][j][r] + bv;
            }
        }
}

// ---------------------------------------------------------------------------
// gif + gib in ONE launch: blockIdx.z picks (W, bias, C). A = xb, M = S*B.
// ---------------------------------------------------------------------------
__global__ __launch_bounds__(256) void gemm_xw2_kernel(
    const u16* __restrict__ A,
    const u16* __restrict__ W0, const u16* __restrict__ W1,
    const float* __restrict__ b0, const float* __restrict__ b1,
    float* __restrict__ C0, float* __restrict__ C1)
{
    const int z = blockIdx.z;
    const u16* Bt = z ? W1 : W0;
    const float* bias = z ? b1 : b0;
    float* C = z ? C1 : C0;
    const int M = S * B, N = H3, K = H;

    __shared__ u16 As[64][40];
    __shared__ u16 Bs[64][40];
    const int m0 = blockIdx.x * 64, n0 = blockIdx.y * 64;
    const int tid = threadIdx.x, wave = tid >> 6, lane = tid & 63;
    const int wm = (wave >> 1) * 32, wn = (wave & 1) * 32;
    const int srow = tid >> 2, scol = (tid & 3) * 8;
    const int fr = lane & 15, kq = lane >> 4;
    f32x4 acc[2][2];
#pragma unroll
    for (int i = 0; i < 2; ++i)
#pragma unroll
        for (int j = 0; j < 2; ++j) acc[i][j] = (f32x4){0.f, 0.f, 0.f, 0.f};

    for (int k0 = 0; k0 < K; k0 += 32) {
        {
            int gr = m0 + srow, gc = k0 + scol;
            bf16x8 v = (bf16x8){0,0,0,0,0,0,0,0};
            if (gr < M && gc + 8 <= K) v = *(const bf16x8*)(A + (long long)gr * K + gc);
            *(bf16x8*)&As[srow][scol] = v;
        }
        {
            int gr = n0 + srow, gc = k0 + scol;
            bf16x8 v = (bf16x8){0,0,0,0,0,0,0,0};
            if (gr < N && gc + 8 <= K) v = *(const bf16x8*)(Bt + (long long)gr * K + gc);
            *(bf16x8*)&Bs[srow][scol] = v;
        }
        __syncthreads();
        bf16x8 af[2], bfr[2];
#pragma unroll
        for (int i = 0; i < 2; ++i) af[i]  = *(const bf16x8*)&As[wm + i * 16 + fr][kq * 8];
#pragma unroll
        for (int j = 0; j < 2; ++j) bfr[j] = *(const bf16x8*)&Bs[wn + j * 16 + fr][kq * 8];
#pragma unroll
        for (int i = 0; i < 2; ++i)
#pragma unroll
            for (int j = 0; j < 2; ++j)
                acc[i][j] = __builtin_amdgcn_mfma_f32_16x16x32_bf16(af[i], bfr[j], acc[i][j], 0, 0, 0);
        __syncthreads();
    }

#pragma unroll
    for (int i = 0; i < 2; ++i)
#pragma unroll
        for (int j = 0; j < 2; ++j) {
            int col = n0 + wn + j * 16 + fr;
            float bv = (col < N) ? bias[col] : 0.f;
#pragma unroll
            for (int r = 0; r < 4; ++r) {
                int row = m0 + wm + i * 16 + kq * 4 + r;
                if (row < M && col < N) C[(long long)row * H3 + col] = acc[i][j][r] + bv;
            }
        }
}

// ---------------------------------------------------------------------------
// Vocab pass B: recompute tile, write FINAL value exp(acc)*sw/rowsum.
// ---------------------------------------------------------------------------
__global__ __launch_bounds__(256) void vocab_write_kernel(
    const u16* __restrict__ A, const u16* __restrict__ Bt,
    const float* __restrict__ swvT, const float* __restrict__ rowsum,
    float* __restrict__ C)
{
    __shared__ u16 As[128][40];
    __shared__ u16 Bs[128][40];
    const int m0 = blockIdx.x * 128, n0 = blockIdx.y * 128;
    const int tid = threadIdx.x, wave = tid >> 6, lane = tid & 63;
    const int wm = (wave >> 1) * 64, wn = (wave & 1) * 64;
    const int srow = tid >> 1, scol = (tid & 1) * 16;
    const int fr = lane & 15, kq = lane >> 4;
    f32x4 acc[4][4];
#pragma unroll
    for (int i = 0; i < 4; ++i)
#pragma unroll
        for (int j = 0; j < 4; ++j) acc[i][j] = (f32x4){0.f, 0.f, 0.f, 0.f};

    for (int k0 = 0; k0 < H; k0 += 32) {
        {
            int gr = m0 + srow, gc = k0 + scol;
            bf16x8 v0 = (bf16x8){0,0,0,0,0,0,0,0}, v1 = v0;
            if (gr < MM) {
                const u16* src = A + (long long)gr * H + gc;
                if (gc + 8 <= H)  v0 = *(const bf16x8*)src;
                if (gc + 16 <= H) v1 = *(const bf16x8*)(src + 8);
            }
            *(bf16x8*)&As[srow][scol] = v0;
            *(bf16x8*)&As[srow][scol + 8] = v1;
        }
        {
            int gr = n0 + srow, gc = k0 + scol;
            bf16x8 v0 = (bf16x8){0,0,0,0,0,0,0,0}, v1 = v0;
            if (gr < V) {
                const u16* src = Bt + (long long)gr * H + gc;
                if (gc + 8 <= H)  v0 = *(const bf16x8*)src;
                if (gc + 16 <= H) v1 = *(const bf16x8*)(src + 8);
            }
            *(bf16x8*)&Bs[srow][scol] = v0;
            *(bf16x8*)&Bs[srow][scol + 8] = v1;
        }
        __syncthreads();
        bf16x8 af[4], bfr[4];
#pragma unroll
        for (int i = 0; i < 4; ++i) af[i]  = *(const bf16x8*)&As[wm + i * 16 + fr][kq * 8];
#pragma unroll
        for (int j = 0; j < 4; ++j) bfr[j] = *(const bf16x8*)&Bs[wn + j * 16 + fr][kq * 8];
#pragma unroll
        for (int i = 0; i < 4; ++i)
#pragma unroll
            for (int j = 0; j < 4; ++j)
                acc[i][j] = __builtin_amdgcn_mfma_f32_16x16x32_bf16(af[i], bfr[j], acc[i][j], 0, 0, 0);
        __syncthreads();
    }

#pragma unroll
    for (int i = 0; i < 4; ++i)
#pragma unroll
        for (int r = 0; r < 4; ++r) {
            int row = m0 + wm + i * 16 + kq * 4 + r;
            float f = 0.f;
            if (row < MM) f = swvT[row] / rowsum[row];
#pragma unroll
            for (int j = 0; j < 4; ++j) {
                int col = n0 + wn + j * 16 + fr;
                if (row < MM && col < V) {
                    int n = row % NB, t = row / NB;
                    C[((long long)n * T + t) * V + col] = __expf(acc[i][j][r]) * f;
                }
            }
        }
}

// ---------------------------------------------------------------------------
// prep_all: emb cvt + 4 weight cvts + encoder weight prep, one grid-stride
// ---------------------------------------------------------------------------
__global__ void prep_all_kernel(
    const float* __restrict__ emb, u16* __restrict__ embb,
    const float* __restrict__ wihf, u16* __restrict__ wihfb,
    const float* __restrict__ wihb, u16* __restrict__ wihbb,
    const float* __restrict__ dwih, u16* __restrict__ dwihb,
    const float* __restrict__ dwhh, u16* __restrict__ dwhhb,
    const float* __restrict__ whhf, const float* __restrict__ whhb,
    u16* __restrict__ wencp)
{
    const int total = NE + 4 * NW + NP;
    for (int i = blockIdx.x * blockDim.x + threadIdx.x; i < total;
         i += gridDim.x * blockDim.x) {
        if (i < NE) { embb[i] = f2bf(emb[i]); continue; }
        int i2 = i - NE;
        if (i2 < NW) { wihfb[i2] = f2bf(wihf[i2]); continue; }
        i2 -= NW;
        if (i2 < NW) { wihbb[i2] = f2bf(wihb[i2]); continue; }
        i2 -= NW;
        if (i2 < NW) { dwihb[i2] = f2bf(dwih[i2]); continue; }
        i2 -= NW;
        if (i2 < NW) { dwhhb[i2] = f2bf(dwhh[i2]); continue; }
        i2 -= NW;
        int k = i2 % EKP; int r = i2 / EKP;
        int rloc = r % EROWS; r /= EROWS;
        int j = r % ENBLK; int dir = r / ENBLK;
        u16 v = 0;
        if (k < H && rloc < 3 * ESL) {
            int g = rloc / ESL, c = rloc % ESL;
            const float* W = dir ? whhb : whhf;
            v = f2bf(W[(long long)(g * H + j * ESL + c) * H + k]);
        }
        wencp[i2] = v;
    }
}

// embed_story + build_decin, one launch
__global__ void embed_decin_kernel(
    const int* __restrict__ story, const u16* __restrict__ embb,
    u16* __restrict__ xb,
    const int* __restrict__ tgt, const int* __restrict__ dom,
    const int* __restrict__ sidx, const float* __restrict__ slt,
    u16* __restrict__ decin)
{
    int row = blockIdx.x;
    if (row < S * B) {
        int s = row >> 4, b = row & 15;
        int tok = story[b * S + s];
        const u16* e = embb + (long long)tok * H;
        u16* d = xb + (long long)row * H;
        for (int k = threadIdx.x; k < H; k += blockDim.x) d[k] = e[k];
    } else {
        int i = row - S * B;
        int t = i / NB, n = i % NB;
        int b = n & 15, slot = n >> 4;
        u16* d = decin + ((long long)t * NB + n) * H;
        if (t == 0) {
            const float* s1 = slt + (long long)dom[slot] * H;
            const float* s2 = slt + (long long)sidx[slot] * H;
            for (int k = threadIdx.x; k < H; k += blockDim.x) d[k] = f2bf(s1[k] + s2[k]);
        } else {
            int tok = tgt[(b * NSLOT + slot) * T + (t - 1)];
            const u16* e = embb + (long long)tok * H;
            for (int k = threadIdx.x; k < H; k += blockDim.x) d[k] = e[k];
        }
    }
}

// ---------------------------------------------------------------------------
// Combined launch: blocks 0..39 = R8-protocol encoder; blocks 40.. = dgi
// GEMM tiles running concurrently on idle CUs. (R12, unchanged)
// ---------------------------------------------------------------------------
__global__ __launch_bounds__(256) void enc_dgi_kernel(
    const u16* __restrict__ wencp,
    const float* __restrict__ bhhf, const float* __restrict__ bhhb,
    const float* __restrict__ gif, const float* __restrict__ gib,
    const int* __restrict__ lens,
    unsigned* __restrict__ hbuf, int* __restrict__ flags,
    float* __restrict__ ysf, float* __restrict__ ysb,
    float* __restrict__ hfo, float* __restrict__ hbo,
    const u16* __restrict__ decinb, const u16* __restrict__ dwhib,
    const float* __restrict__ dbih, float* __restrict__ dgi)
{
    __shared__ __align__(16) char ldsu[EROWS * EKP * 2 + EROWS * 17 * 4];
    const int tid = threadIdx.x, wave = tid >> 6, lane = tid & 63;
    const int fr = lane & 15, kq = lane >> 4;

    if (blockIdx.x >= ENC_BLOCKS) {
        u16* As = (u16*)ldsu;
        u16* Bs = As + 64 * 40;
        const int tile = blockIdx.x - ENC_BLOCKS;
        const int m0 = (tile % DGI_TM) * 64, n0 = (tile / DGI_TM) * 64;
        const int wm = (wave >> 1) * 32, wn = (wave & 1) * 32;
        const int srow = tid >> 2, scol = (tid & 3) * 8;
        f32x4 acc[2][2];
#pragma unroll
        for (int i = 0; i < 2; ++i)
#pragma unroll
            for (int j = 0; j < 2; ++j) acc[i][j] = (f32x4){0.f, 0.f, 0.f, 0.f};

        for (int k0 = 0; k0 < H; k0 += 32) {
            {
                int gr = m0 + srow, gc = k0 + scol;
                bf16x8 v = (bf16x8){0,0,0,0,0,0,0,0};
                if (gr < MM && gc + 8 <= H) v = *(const bf16x8*)(decinb + (long long)gr * H + gc);
                *(bf16x8*)&As[srow * 40 + scol] = v;
            }
            {
                int gr = n0 + srow, gc = k0 + scol;
                bf16x8 v = (bf16x8){0,0,0,0,0,0,0,0};
                if (gr < H3 && gc + 8 <= H) v = *(const bf16x8*)(dwhib + (long long)gr * H + gc);
                *(bf16x8*)&Bs[srow * 40 + scol] = v;
            }
            __syncthreads();
            bf16x8 af[2], bfr[2];
#pragma unroll
            for (int i = 0; i < 2; ++i) af[i]  = *(const bf16x8*)&As[(wm + i * 16 + fr) * 40 + kq * 8];
#pragma unroll
            for (int j = 0; j < 2; ++j) bfr[j] = *(const bf16x8*)&Bs[(wn + j * 16 + fr) * 40 + kq * 8];
#pragma unroll
            for (int i = 0; i < 2; ++i)
#pragma unroll
                for (int j = 0; j < 2; ++j)
                    acc[i][j] = __builtin_amdgcn_mfma_f32_16x16x32_bf16(af[i], bfr[j], acc[i][j], 0, 0, 0);
            __syncthreads();
        }
#pragma unroll
        for (int i = 0; i < 2; ++i)
#pragma unroll
            for (int j = 0; j < 2; ++j) {
                int col = n0 + wn + j * 16 + fr;
                float bv = (col < H3) ? dbih[col] : 0.f;
#pragma unroll
                for (int r = 0; r < 4; ++r) {
                    int row = m0 + wm + i * 16 + kq * 4 + r;
                    if (row < MM && col < H3) dgi[(long long)row * H3 + col] = acc[i][j][r] + bv;
                }
            }
        return;
    }

    u16* wlds = (u16*)ldsu;
    float* ghs = (float*)(ldsu + EROWS * EKP * 2);
    const int bid = blockIdx.x;
    const int dir = bid / ENBLK, j = bid % ENBLK;
    const float* bhh = dir ? bhhb : bhhf;
    const float* gi  = dir ? gib  : gif;
    float* ys = dir ? ysb : ysf;
    float* ho = dir ? hbo : hfo;

    const u16* wsrc = wencp + (long long)(dir * ENBLK + j) * EROWS * EKP;
    for (int i = tid * 8; i < EROWS * EKP; i += 256 * 8)
        *(bf16x8*)&wlds[i] = *(const bf16x8*)&wsrc[i];
    for (int i = tid; i < EROWS * 17; i += 256) ghs[i] = 0.f;

    const int p0 = tid, p1 = 256 + tid;
    const bool has1 = (tid < 64);
    const int b0 = p0 / ESL, kl0 = p0 % ESL;
    const int b1 = has1 ? p1 / ESL : 0, kl1 = has1 ? p1 % ESL : 0;
    const int k0 = j * ESL;
    const int len0 = lens[b0];
    const int len1 = has1 ? lens[b1] : 0;
    const float bhr0 = bhh[k0 + kl0], bhz0 = bhh[H + k0 + kl0], bhn0 = bhh[2 * H + k0 + kl0];
    const float bhr1 = has1 ? bhh[k0 + kl1] : 0.f;
    const float bhz1 = has1 ? bhh[H + k0 + kl1] : 0.f;
    const float bhn1 = has1 ? bhh[2 * H + k0 + kl1] : 0.f;
    float h0r = 0.f, h1r = 0.f;

    unsigned* hb_d = hbuf + (long long)dir * S * B * EKP;
    int* flg_d = flags + dir * S * ENBLK;
    const u16* arow = &wlds[(wave * 16 + fr) * EKP + kq * 8];
    __syncthreads();

    for (int t = 0; t < S; ++t) {
        const int s = dir ? (S - 1 - t) : t;
        const float* gbase = gi + (long long)s * B * H3;
        float gr0 = gbase[b0 * H3 + k0 + kl0];
        float gz0 = gbase[b0 * H3 + H + k0 + kl0];
        float gn0 = gbase[b0 * H3 + 2 * H + k0 + kl0];
        float gr1 = 0.f, gz1 = 0.f, gn1 = 0.f;
        if (has1) {
            gr1 = gbase[b1 * H3 + k0 + kl1];
            gz1 = gbase[b1 * H3 + H + k0 + kl1];
            gn1 = gbase[b1 * H3 + 2 * H + k0 + kl1];
        }

        f32x4 acc = (f32x4){0.f, 0.f, 0.f, 0.f};
        if (t > 0) {
            const int* fl = flg_d + (t - 1) * ENBLK;
            for (;;) {
                int v = 1;
                if (lane < ENBLK)
                    v = __hip_atomic_load(&fl[lane], __ATOMIC_RELAXED,
                                          __HIP_MEMORY_SCOPE_AGENT);
                if (__all(v != 0)) break;
                __builtin_amdgcn_s_sleep(2);
            }
            asm volatile("" ::: "memory");
            const unsigned* hrow = hb_d + ((long long)(t - 1) * B + fr) * EKP + kq * 8;
            f32x4 acch = (f32x4){0.f, 0.f, 0.f, 0.f};
            f32x4 accl = (f32x4){0.f, 0.f, 0.f, 0.f};
#pragma unroll
            for (int kk = 0; kk < 13; ++kk) {
                u32x4 a = *(const u32x4*)(hrow + kk * 32);
                u32x4 b = *(const u32x4*)(hrow + kk * 32 + 4);
                union { unsigned u[4]; bf16x8 v; } hi, lo;
                hi.u[0] = __builtin_amdgcn_perm(a[1], a[0], 0x05040100u);
                hi.u[1] = __builtin_amdgcn_perm(a[3], a[2], 0x05040100u);
                hi.u[2] = __builtin_amdgcn_perm(b[1], b[0], 0x05040100u);
                hi.u[3] = __builtin_amdgcn_perm(b[3], b[2], 0x05040100u);
                lo.u[0] = __builtin_amdgcn_perm(a[1], a[0], 0x07060302u);
                lo.u[1] = __builtin_amdgcn_perm(a[3], a[2], 0x07060302u);
                lo.u[2] = __builtin_amdgcn_perm(b[1], b[0], 0x07060302u);
                lo.u[3] = __builtin_amdgcn_perm(b[3], b[2], 0x07060302u);
                bf16x8 av = *(const bf16x8*)(arow + kk * 32);
                acch = __builtin_amdgcn_mfma_f32_16x16x32_bf16(av, hi.v, acch, 0, 0, 0);
                accl = __builtin_amdgcn_mfma_f32_16x16x32_bf16(av, lo.v, accl, 0, 0, 0);
            }
            acc = acch + accl;
        }
#pragma unroll
        for (int r = 0; r < 4; ++r) ghs[(wave * 16 + kq * 4 + r) * 17 + fr] = acc[r];
        __syncthreads();

        unsigned* hpub = hb_d + (long long)t * B * EKP;
        {
            float ghr = ghs[kl0 * 17 + b0];
            float ghz = ghs[(ESL + kl0) * 17 + b0];
            float ghn = ghs[(2 * ESL + kl0) * 17 + b0];
            float rg = sigm(gr0 + ghr + bhr0);
            float zg = sigm(gz0 + ghz + bhz0);
            float ng = tanhf(gn0 + rg * (ghn + bhn0));
            float hn = (1.f - zg) * ng + zg * h0r;
            bool msk = s < len0;
            float y = msk ? hn : 0.f;
            if (msk) h0r = hn;
            ys[((long long)(b0 * S + s)) * H + k0 + kl0] = y;
            u16 hi = f2bf(h0r);
            unsigned packed = (unsigned)hi | ((unsigned)f2bf(h0r - bf2f(hi)) << 16);
            __hip_atomic_store(&hpub[b0 * EKP + k0 + kl0], packed, __ATOMIC_RELAXED,
                               __HIP_MEMORY_SCOPE_AGENT);
        }
        if (has1) {
            float ghr = ghs[kl1 * 17 + b1];
            float ghz = ghs[(ESL + kl1) * 17 + b1];
            float ghn = ghs[(2 * ESL + kl1) * 17 + b1];
            float rg = sigm(gr1 + ghr + bhr1);
            float zg = sigm(gz1 + ghz + bhz1);
            float ng = tanhf(gn1 + rg * (ghn + bhn1));
            float hn = (1.f - zg) * ng + zg * h1r;
            bool msk = s < len1;
            float y = msk ? hn : 0.f;
            if (msk) h1r = hn;
            ys[((long long)(b1 * S + s)) * H + k0 + kl1] = y;
            u16 hi = f2bf(h1r);
            unsigned packed = (unsigned)hi | ((unsigned)f2bf(h1r - bf2f(hi)) << 16);
            __hip_atomic_store(&hpub[b1 * EKP + k0 + kl1], packed, __ATOMIC_RELAXED,
                               __HIP_MEMORY_SCOPE_AGENT);
        }
        __syncthreads();
        if (tid == 0)
            __hip_atomic_store(&flg_d[t * ENBLK + j], 1, __ATOMIC_RELAXED,
                               __HIP_MEMORY_SCOPE_AGENT);
    }
    ho[b0 * H + k0 + kl0] = h0r;
    if (has1) ho[b1 * H + k0 + kl1] = h1r;
}

// packE + h0 merged: blocks 0..127 = packE tiles, 128..607 = h0 rows
__global__ __launch_bounds__(256) void packE_h0_kernel(
    const float* __restrict__ ysf, const float* __restrict__ ysb,
    u16* __restrict__ E, u16* __restrict__ ET,
    const float* __restrict__ hf, const float* __restrict__ hb,
    float* __restrict__ hf32, u16* __restrict__ hnk)
{
    __shared__ u16 tile[32][400];
    const int blk = blockIdx.x;
    if (blk < B * (S / 32)) {
        const int b = blk / (S / 32), s0 = (blk % (S / 32)) * 32;
        for (int si = 0; si < 32; ++si) {
            const long long base = ((long long)b * S + s0 + si) * H;
            for (int k = threadIdx.x; k < H; k += blockDim.x) {
                u16 v = f2bf(ysf[base + k] + ysb[base + k]);
                E[base + k] = v;
                tile[si][k] = v;
            }
        }
        __syncthreads();
        for (int idx = threadIdx.x; idx < 32 * H; idx += blockDim.x) {
            int k = idx >> 5, si = idx & 31;
            ET[((long long)b * H + k) * S + s0 + si] = tile[si][k];
        }
    } else {
        int n = blk - B * (S / 32), b = n & 15;
        for (int k = threadIdx.x; k < H; k += blockDim.x) {
            float v = hf[b * H + k] + hb[b * H + k];
            hf32[(long long)n * H + k] = v;
            hnk[(long long)n * H + k] = f2bf(v);
        }
    }
}

// ---------------------------------------------------------------------------
// A_t: blocks 0..749 = GRU cell for step t; blocks 750..1377 = vocab rowsum
// tiles for step t-1 (A = hall[t-1], written 2 dispatches ago; atomicAdd
// into rowsumT[(t-1)*NB + row]). Skipped at t==0.
// ---------------------------------------------------------------------------
__global__ __launch_bounds__(256) void cell_rowsum_kernel(
    const float* __restrict__ dgi, const float* __restrict__ dgh,
    float* __restrict__ hf32, u16* __restrict__ hall,
    const u16* __restrict__ embb, float* __restrict__ rowsumT, int t)
{
    if (blockIdx.x < CELL_BLOCKS) {
        const int total = NB * H;
        for (int i = blockIdx.x * 256 + threadIdx.x; i < total; i += CELL_BLOCKS * 256) {
            int n = i / H, k = i % H;
            const float* gi = dgi + ((long long)t * NB + n) * H3;
            const float* gh = dgh + (long long)n * H3;
            float r  = sigm(gi[k] + gh[k]);
            float z  = sigm(gi[H + k] + gh[H + k]);
            float nn = tanhf(gi[2 * H + k] + r * gh[2 * H + k]);
            float h  = hf32[i];
            float hn = (1.f - z) * nn + z * h;
            hf32[i] = hn;
            hall[((long long)t * NB + n) * H + k] = f2bf(hn);
        }
        return;
    }
    if (t == 0) return;
    // rowsum role: 128x128 tile for step t-1
    __shared__ u16 As[128][40];
    __shared__ u16 Bs[128][40];
    const int tile = blockIdx.x - CELL_BLOCKS;
    const int m0l = (tile % RS_TM) * 128, n0 = (tile / RS_TM) * 128;
    const u16* A = hall + (long long)(t - 1) * NB * H;
    float* rowsum = rowsumT + (long long)(t - 1) * NB;
    const int tid = threadIdx.x, wave = tid >> 6, lane = tid & 63;
    const int wm = (wave >> 1) * 64, wn = (wave & 1) * 64;
    const int srow = tid >> 1, scol = (tid & 1) * 16;
    const int fr = lane & 15, kq = lane >> 4;
    f32x4 acc[4][4];
#pragma unroll
    for (int i = 0; i < 4; ++i)
#pragma unroll
        for (int j = 0; j < 4; ++j) acc[i][j] = (f32x4){0.f, 0.f, 0.f, 0.f};

    for (int k0 = 0; k0 < H; k0 += 32) {
        {
            int gr = m0l + srow, gc = k0 + scol;
            bf16x8 v0 = (bf16x8){0,0,0,0,0,0,0,0}, v1 = v0;
            if (gr < NB) {
                const u16* src = A + (long long)gr * H + gc;
                if (gc + 8 <= H)  v0 = *(const bf16x8*)src;
                if (gc + 16 <= H) v1 = *(const bf16x8*)(src + 8);
            }
            *(bf16x8*)&As[srow][scol] = v0;
            *(bf16x8*)&As[srow][scol + 8] = v1;
        }
        {
            int gr = n0 + srow, gc = k0 + scol;
            bf16x8 v0 = (bf16x8){0,0,0,0,0,0,0,0}, v1 = v0;
            if (gr < V) {
                const u16* src = embb + (long long)gr * H + gc;
                if (gc + 8 <= H)  v0 = *(const bf16x8*)src;
                if (gc + 16 <= H) v1 = *(const bf16x8*)(src + 8);
            }
            *(bf16x8*)&Bs[srow][scol] = v0;
            *(bf16x8*)&Bs[srow][scol + 8] = v1;
        }
        __syncthreads();
        bf16x8 af[4], bfr[4];
#pragma unroll
        for (int i = 0; i < 4; ++i) af[i]  = *(const bf16x8*)&As[wm + i * 16 + fr][kq * 8];
#pragma unroll
        for (int j = 0; j < 4; ++j) bfr[j] = *(const bf16x8*)&Bs[wn + j * 16 + fr][kq * 8];
#pragma unroll
        for (int i = 0; i < 4; ++i)
#pragma unroll
            for (int j = 0; j < 4; ++j)
                acc[i][j] = __builtin_amdgcn_mfma_f32_16x16x32_bf16(af[i], bfr[j], acc[i][j], 0, 0, 0);
        __syncthreads();
    }

#pragma unroll
    for (int i = 0; i < 4; ++i)
#pragma unroll
        for (int r = 0; r < 4; ++r) {
            int row = m0l + wm + i * 16 + kq * 4 + r;
            float s = 0.f;
#pragma unroll
            for (int j = 0; j < 4; ++j) {
                int col = n0 + wn + j * 16 + fr;
                if (row < NB && col < V) s += __expf(acc[i][j][r]);
            }
            s += __shfl_xor(s, 1); s += __shfl_xor(s, 2);
            s += __shfl_xor(s, 4); s += __shfl_xor(s, 8);
            if (fr == 0 && row < NB) atomicAdd(&rowsum[row], s);
        }
}

// ---------------------------------------------------------------------------
// B_t: blocks 0..151 = dgh GEMM tiles for step t+1 (plain stores, consumed
// next dispatch); at t==T-1 they instead sweep the step-T-1 rowsum tiles.
// blocks 152..167 = attention for step t.
// ---------------------------------------------------------------------------
__global__ __launch_bounds__(512) void dec_attn_kernel(
    const u16* __restrict__ hall, const u16* __restrict__ dwhhb,
    const float* __restrict__ dbhh, float* __restrict__ dgh,
    const u16* __restrict__ decinb, const u16* __restrict__ embb,
    const u16* __restrict__ Eb, const u16* __restrict__ ETb,
    const int* __restrict__ lens,
    const float* __restrict__ Wr, const float* __restrict__ br,
    const float* __restrict__ Wg, const float* __restrict__ bg,
    float* __restrict__ probfT, float* __restrict__ swvT,
    float* __restrict__ rowsumT, float* __restrict__ gout, int t)
{
    extern __shared__ char smem[];
    const int tid = threadIdx.x, wave = tid >> 6, lane = tid & 63;
    const int fr = lane & 15, kq = lane >> 4;
    const u16* hcur = hall + (long long)t * NB * H;

    if (blockIdx.x < DGH_TILES) {
        if (t < T - 1) {
            // ---------------- dgh tile role (for step t+1) ----------------
            u16* As = (u16*)smem;              // [64][40]
            u16* Bs = As + 64 * 40;            // [64][40]
            const int tile = blockIdx.x;
            const int m0 = (tile % DGH_TM) * 64, n0 = (tile / DGH_TM) * 64;
            const bool act = (wave < 4);
            const int wm = (wave >> 1) * 32, wn = (wave & 1) * 32;
            const int srow = tid >> 2, scol = (tid & 3) * 8;
            f32x4 acc[2][2];
#pragma unroll
            for (int i = 0; i < 2; ++i)
#pragma unroll
                for (int j = 0; j < 2; ++j) acc[i][j] = (f32x4){0.f, 0.f, 0.f, 0.f};

            for (int k0 = 0; k0 < H; k0 += 32) {
                if (tid < 256) {
                    {
                        int gr = m0 + srow, gc = k0 + scol;
                        bf16x8 v = (bf16x8){0,0,0,0,0,0,0,0};
                        if (gr < NB && gc + 8 <= H) v = *(const bf16x8*)(hcur + (long long)gr * H + gc);
                        *(bf16x8*)&As[srow * 40 + scol] = v;
                    }
                    {
                        int gr = n0 + srow, gc = k0 + scol;
                        bf16x8 v = (bf16x8){0,0,0,0,0,0,0,0};
                        if (gr < H3 && gc + 8 <= H) v = *(const bf16x8*)(dwhhb + (long long)gr * H + gc);
                        *(bf16x8*)&Bs[srow * 40 + scol] = v;
                    }
                }
                __syncthreads();
                if (act) {
                    bf16x8 af[2], bfr[2];
#pragma unroll
                    for (int i = 0; i < 2; ++i) af[i]  = *(const bf16x8*)&As[(wm + i * 16 + fr) * 40 + kq * 8];
#pragma unroll
                    for (int j = 0; j < 2; ++j) bfr[j] = *(const bf16x8*)&Bs[(wn + j * 16 + fr) * 40 + kq * 8];
#pragma unroll
                    for (int i = 0; i < 2; ++i)
#pragma unroll
                        for (int j = 0; j < 2; ++j)
                            acc[i][j] = __builtin_amdgcn_mfma_f32_16x16x32_bf16(af[i], bfr[j], acc[i][j], 0, 0, 0);
                }
                __syncthreads();
            }
            if (act) {
#pragma unroll
                for (int i = 0; i < 2; ++i)
#pragma unroll
                    for (int j = 0; j < 2; ++j) {
                        int col = n0 + wn + j * 16 + fr;
                        float bv = (col < H3) ? dbhh[col] : 0.f;
#pragma unroll
                        for (int r = 0; r < 4; ++r) {
                            int row = m0 + wm + i * 16 + kq * 4 + r;
                            if (row < NB && col < H3)
                                dgh[(long long)row * H3 + col] = acc[i][j][r] + bv;
                        }
                    }
            }
            return;
        }
        // ---------------- t == T-1: rowsum tiles for step T-1 ----------------
        u16* As = (u16*)smem;              // [128][40]
        u16* Bs = As + 128 * 40;           // [128][40]
        const u16* A = hcur;
        float* rowsum = rowsumT + (long long)t * NB;
        const bool act = (wave < 4);
        const int wm = (wave >> 1) * 64, wn = (wave & 1) * 64;
        const int srow = tid >> 1, scol = (tid & 1) * 16;
        for (int tile = blockIdx.x; tile < RS_TILES; tile += DGH_TILES) {
            const int m0l = (tile % RS_TM) * 128, n0 = (tile / RS_TM) * 128;
            f32x4 acc[4][4];
#pragma unroll
            for (int i = 0; i < 4; ++i)
#pragma unroll
                for (int j = 0; j < 4; ++j) acc[i][j] = (f32x4){0.f, 0.f, 0.f, 0.f};
            for (int k0 = 0; k0 < H; k0 += 32) {
                if (tid < 256) {
                    {
                        int gr = m0l + srow, gc = k0 + scol;
                        bf16x8 v0 = (bf16x8){0,0,0,0,0,0,0,0}, v1 = v0;
                        if (gr < NB) {
                            const u16* src = A + (long long)gr * H + gc;
                            if (gc + 8 <= H)  v0 = *(const bf16x8*)src;
                            if (gc + 16 <= H) v1 = *(const bf16x8*)(src + 8);
                        }
                        *(bf16x8*)&As[srow * 40 + scol] = v0;
                        *(bf16x8*)&As[srow * 40 + scol + 8] = v1;
                    }
                    {
                        int gr = n0 + srow, gc = k0 + scol;
                        bf16x8 v0 = (bf16x8){0,0,0,0,0,0,0,0}, v1 = v0;
                        if (gr < V) {
                            const u16* src = embb + (long long)gr * H + gc;
                            if (gc + 8 <= H)  v0 = *(const bf16x8*)src;
                            if (gc + 16 <= H) v1 = *(const bf16x8*)(src + 8);
                        }
                        *(bf16x8*)&Bs[srow * 40 + scol] = v0;
                        *(bf16x8*)&Bs[srow * 40 + scol + 8] = v1;
                    }
                }
                __syncthreads();
                if (act) {
                    bf16x8 af[4], bfr[4];
#pragma unroll
                    for (int i = 0; i < 4; ++i) af[i]  = *(const bf16x8*)&As[(wm + i * 16 + fr) * 40 + kq * 8];
#pragma unroll
                    for (int j = 0; j < 4; ++j) bfr[j] = *(const bf16x8*)&Bs[(wn + j * 16 + fr) * 40 + kq * 8];
#pragma unroll
                    for (int i = 0; i < 4; ++i)
#pragma unroll
                        for (int j = 0; j < 4; ++j)
                            acc[i][j] = __builtin_amdgcn_mfma_f32_16x16x32_bf16(af[i], bfr[j], acc[i][j], 0, 0, 0);
                }
                __syncthreads();
            }
            if (act) {
#pragma unroll
                for (int i = 0; i < 4; ++i)
#pragma unroll
                    for (int r = 0; r < 4; ++r) {
                        int row = m0l + wm + i * 16 + kq * 4 + r;
                        float s = 0.f;
#pragma unroll
                        for (int j = 0; j < 4; ++j) {
                            int col = n0 + wn + j * 16 + fr;
                            if (row < NB && col < V) s += __expf(acc[i][j][r]);
                        }
                        s += __shfl_xor(s, 1); s += __shfl_xor(s, 2);
                        s += __shfl_xor(s, 4); s += __shfl_xor(s, 8);
                        if (fr == 0 && row < NB) atomicAdd(&rowsum[row], s);
                    }
            }
            __syncthreads();
        }
        return;
    }

    // -------------------- attention role --------------------
    u16*   hls = (u16*)smem;                                   // [32][HP2]
    float* scs = (float*)(smem + 32 * HP2 * 2);                // [32][SCP]
    u16*   pls = (u16*)(smem + 32 * HP2 * 2 + 32 * SCP * 4);   // [32][PP]
    float* cxs = (float*)(smem + 32 * HP2 * 2 + 32 * SCP * 4 + 32 * PP * 2); // [32][CXP]

    const int b = blockIdx.x - DGH_TILES;
    const int len = lens[b];

    for (int i = tid; i < 32 * (HP2 - H); i += 512) {
        int r = i / (HP2 - H), c = H + i % (HP2 - H);
        hls[r * HP2 + c] = 0;
    }
    for (int i = tid; i < 2 * HP2; i += 512) hls[30 * HP2 + i] = 0;
    for (int i = tid; i < 2 * PP; i += 512) pls[30 * PP + i] = 0;

    for (int i = tid; i < 30 * H; i += 512) {
        int slot = i / H, k = i % H;
        hls[slot * HP2 + k] = hcur[((long long)(slot * 16 + b)) * H + k];
    }
    __syncthreads();

    // P1: scores
    {
        const int nt0 = wave * 2;
        f32x4 acc[2][2];
#pragma unroll
        for (int i = 0; i < 2; ++i)
#pragma unroll
            for (int jj = 0; jj < 2; ++jj) acc[i][jj] = (f32x4){0.f, 0.f, 0.f, 0.f};
        const u16* br0 = Eb + ((long long)b * S + nt0 * 16 + fr) * H + kq * 8;
        const u16* br1 = Eb + ((long long)b * S + (nt0 + 1) * 16 + fr) * H + kq * 8;
        const u16* ar0 = hls + fr * HP2 + kq * 8;
        const u16* ar1 = hls + (16 + fr) * HP2 + kq * 8;
#pragma unroll
        for (int kk = 0; kk < 13; ++kk) {
            bf16x8 av0 = *(const bf16x8*)(ar0 + kk * 32);
            bf16x8 av1 = *(const bf16x8*)(ar1 + kk * 32);
            bf16x8 bv0, bv1;
            if (kk == 12 && kq >= 2) {
                bv0 = (bf16x8){0,0,0,0,0,0,0,0}; bv1 = bv0;
            } else {
                bv0 = *(const bf16x8*)(br0 + kk * 32);
                bv1 = *(const bf16x8*)(br1 + kk * 32);
            }
            acc[0][0] = __builtin_amdgcn_mfma_f32_16x16x32_bf16(av0, bv0, acc[0][0], 0, 0, 0);
            acc[1][0] = __builtin_amdgcn_mfma_f32_16x16x32_bf16(av1, bv0, acc[1][0], 0, 0, 0);
            acc[0][1] = __builtin_amdgcn_mfma_f32_16x16x32_bf16(av0, bv1, acc[0][1], 0, 0, 0);
            acc[1][1] = __builtin_amdgcn_mfma_f32_16x16x32_bf16(av1, bv1, acc[1][1], 0, 0, 0);
        }
#pragma unroll
        for (int i = 0; i < 2; ++i)
#pragma unroll
            for (int jj = 0; jj < 2; ++jj)
#pragma unroll
                for (int r = 0; r < 4; ++r)
                    scs[(i * 16 + kq * 4 + r) * SCP + (nt0 + jj) * 16 + fr] = acc[i][jj][r];
    }
    __syncthreads();

    // P2: softmax
    for (int i = 0; i < 4; ++i) {
        int row = wave * 4 + i;
        if (row >= 30) break;
        int n = row * 16 + b;
        float v[4];
        float mx = -3.0e38f;
#pragma unroll
        for (int q = 0; q < 4; ++q) {
            int s = lane + 64 * q;
            float x = (s < len) ? scs[row * SCP + s] : -3.0e38f;
            v[q] = x; mx = fmaxf(mx, x);
        }
        mx = fmaxf(mx, __shfl_xor(mx, 1));  mx = fmaxf(mx, __shfl_xor(mx, 2));
        mx = fmaxf(mx, __shfl_xor(mx, 4));  mx = fmaxf(mx, __shfl_xor(mx, 8));
        mx = fmaxf(mx, __shfl_xor(mx, 16)); mx = fmaxf(mx, __shfl_xor(mx, 32));
        float sum = 0.f;
#pragma unroll
        for (int q = 0; q < 4; ++q) {
            int s = lane + 64 * q;
            float e = (s < len) ? __expf(v[q] - mx) : 0.f;
            v[q] = e; sum += e;
        }
        sum += __shfl_xor(sum, 1);  sum += __shfl_xor(sum, 2);
        sum += __shfl_xor(sum, 4);  sum += __shfl_xor(sum, 8);
        sum += __shfl_xor(sum, 16); sum += __shfl_xor(sum, 32);
        float inv = 1.f / sum;
#pragma unroll
        for (int q = 0; q < 4; ++q) {
            int s = lane + 64 * q;
            float pr = v[q] * inv;
            pls[row * PP + s] = f2bf(pr);
            probfT[((long long)(t * NB + n)) * S + s] = pr;
        }
    }
    __syncthreads();

    // P3: ctx
    for (int nt = wave; nt < 25; nt += 8) {
        f32x4 acc0 = (f32x4){0.f,0.f,0.f,0.f}, acc1 = (f32x4){0.f,0.f,0.f,0.f};
        const u16* brow = ETb + ((long long)b * H + nt * 16 + fr) * S + kq * 8;
        const u16* ar0 = pls + fr * PP + kq * 8;
        const u16* ar1 = pls + (16 + fr) * PP + kq * 8;
#pragma unroll
        for (int kk = 0; kk < 8; ++kk) {
            bf16x8 bv  = *(const bf16x8*)(brow + kk * 32);
            bf16x8 av0 = *(const bf16x8*)(ar0 + kk * 32);
            bf16x8 av1 = *(const bf16x8*)(ar1 + kk * 32);
            acc0 = __builtin_amdgcn_mfma_f32_16x16x32_bf16(av0, bv, acc0, 0, 0, 0);
            acc1 = __builtin_amdgcn_mfma_f32_16x16x32_bf16(av1, bv, acc1, 0, 0, 0);
        }
#pragma unroll
        for (int r = 0; r < 4; ++r) {
            cxs[(kq * 4 + r) * CXP + nt * 16 + fr] = acc0[r];
            cxs[(16 + kq * 4 + r) * CXP + nt * 16 + fr] = acc1[r];
        }
    }
    __syncthreads();

    // P4: p_gen (+ gate at t==0)
    for (int i = 0; i < 4; ++i) {
        int slot = wave + 8 * i;
        if (slot >= 30) break;
        int n = slot * 16 + b;
        const u16* xrow = decinb + ((long long)t * NB + n) * H;
        float p = 0.f;
        for (int k = lane; k < H; k += 64)
            p += bf2f(hls[slot * HP2 + k]) * Wr[k]
               + cxs[slot * CXP + k] * Wr[H + k]
               + bf2f(xrow[k]) * Wr[2 * H + k];
        p += __shfl_xor(p, 1);  p += __shfl_xor(p, 2);
        p += __shfl_xor(p, 4);  p += __shfl_xor(p, 8);
        p += __shfl_xor(p, 16); p += __shfl_xor(p, 32);
        if (lane == 0) swvT[t * NB + n] = sigm(p + br[0]);
        if (t == 0) {
            for (int g = 0; g < G; ++g) {
                float q = 0.f;
                for (int k = lane; k < H; k += 64)
                    q += cxs[slot * CXP + k] * Wg[g * H + k];
                q += __shfl_xor(q, 1);  q += __shfl_xor(q, 2);
                q += __shfl_xor(q, 4);  q += __shfl_xor(q, 8);
                q += __shfl_xor(q, 16); q += __shfl_xor(q, 32);
                if (lane == 0) gout[(long long)n * G + g] = q + bg[g];
            }
        }
    }
}

__global__ void scatter_all_kernel(float* __restrict__ out, const int* __restrict__ story,
                                   const int* __restrict__ lens, const float* __restrict__ swvT,
                                   const float* __restrict__ probfT) {
    const int n = blockIdx.x, t = blockIdx.y, b = n & 15, s = threadIdx.x;
    if (s < lens[b]) {
        int tok = story[b * S + s];
        atomicAdd(out + ((long long)n * T + t) * V + tok,
                  (1.f - swvT[t * NB + n]) * probfT[((long long)(t * NB + n)) * S + s]);
    }
}

// ---------------------------------------------------------------------------
extern "C" void kernel_launch(void* const* d_in, const int* in_sizes, int n_in,
                              void* d_out, int out_size, void* d_ws, size_t ws_size,
                              hipStream_t stream) {
    const int*   story = (const int*)d_in[0];
    const int*   lens  = (const int*)d_in[1];
    const int*   tgt   = (const int*)d_in[2];
    const int*   dom   = (const int*)d_in[3];
    const int*   sidx  = (const int*)d_in[4];
    const float* emb   = (const float*)d_in[5];
    const float* wihf  = (const float*)d_in[6];
    const float* whhf  = (const float*)d_in[7];
    const float* bihf  = (const float*)d_in[8];
    const float* bhhf  = (const float*)d_in[9];
    const float* wihb  = (const float*)d_in[10];
    const float* whhb  = (const float*)d_in[11];
    const float* bihb  = (const float*)d_in[12];
    const float* bhhb  = (const float*)d_in[13];
    const float* dwih  = (const float*)d_in[14];
    const float* dwhh  = (const float*)d_in[15];
    const float* dbih  = (const float*)d_in[16];
    const float* dbhh  = (const float*)d_in[17];
    const float* Wr    = (const float*)d_in[18];
    const float* br    = (const float*)d_in[19];
    const float* Wg    = (const float*)d_in[20];
    const float* bg    = (const float*)d_in[21];
    const float* slt   = (const float*)d_in[22];
    float* out = (float*)d_out;

    char* wsb = (char*)d_ws;
    size_t off = 0;
    auto alloc = [&](size_t bytes) -> char* {
        char* p = wsb + off;
        off += (bytes + 255) & ~(size_t)255;
        return p;
    };
    u16*   embb   = (u16*)alloc((size_t)V * H * 2);
    u16*   wihfb  = (u16*)alloc((size_t)H3 * H * 2);
    u16*   wihbb  = (u16*)alloc((size_t)H3 * H * 2);
    u16*   dwihb  = (u16*)alloc((size_t)H3 * H * 2);
    u16*   dwhhb  = (u16*)alloc((size_t)H3 * H * 2);
    u16*   wencp  = (u16*)alloc((size_t)2 * ENBLK * EROWS * EKP * 2);
    unsigned* hbuf = (unsigned*)alloc((size_t)2 * S * B * EKP * 4);
    int*   flags  = (int*)alloc((size_t)2 * S * ENBLK * 4);
    u16*   xb     = (u16*)alloc((size_t)S * B * H * 2);
    u16*   decinb = (u16*)alloc((size_t)T * NB * H * 2);
    float* gif    = (float*)alloc((size_t)S * B * H3 * 4);
    float* gib    = (float*)alloc((size_t)S * B * H3 * 4);
    float* dgi    = (float*)alloc((size_t)T * NB * H3 * 4);
    float* ysf    = (float*)alloc((size_t)B * S * H * 4);
    float* ysb    = (float*)alloc((size_t)B * S * H * 4);
    float* hfv    = (float*)alloc((size_t)B * H * 4);
    float* hbv    = (float*)alloc((size_t)B * H * 4);
    u16*   Eb     = (u16*)alloc((size_t)B * S * H * 2);
    u16*   ETb    = (u16*)alloc((size_t)B * H * S * 2);
    float* hf32   = (float*)alloc((size_t)NB * H * 4);
    u16*   hnk    = (u16*)alloc((size_t)NB * H * 2);
    u16*   hall   = (u16*)alloc((size_t)T * NB * H * 2);
    float* dgh    = (float*)alloc((size_t)NB * H3 * 4);
    float* probfT = (float*)alloc((size_t)T * NB * S * 4);
    float* swvT   = (float*)alloc((size_t)T * NB * 4);
    float* rowsumT = (float*)alloc((size_t)T * NB * 4);
    (void)ws_size; (void)in_sizes; (void)n_in; (void)out_size;

    hipFuncSetAttribute((const void*)dec_attn_kernel,
                        hipFuncAttributeMaxDynamicSharedMemorySize, FUSED_LDS);

    // ---- setup ------------------------------------------------------------
    hipMemsetAsync(flags, 0, (size_t)2 * S * ENBLK * 4, stream);
    hipMemsetAsync(hbuf, 0, (size_t)2 * S * B * EKP * 4, stream);
    hipMemsetAsync(rowsumT, 0, (size_t)T * NB * 4, stream);
    prep_all_kernel<<<2048, 256, 0, stream>>>(emb, embb, wihf, wihfb, wihb, wihbb,
                                              dwih, dwihb, dwhh, dwhhb,
                                              whhf, whhb, wencp);
    embed_decin_kernel<<<S * B + T * NB, 256, 0, stream>>>(
        story, embb, xb, tgt, dom, sidx, slt, decinb);
    {
        dim3 g((S * B + 63) / 64, (H3 + 63) / 64, 2);
        gemm_xw2_kernel<<<g, 256, 0, stream>>>(xb, wihfb, wihbb, bihf, bihb, gif, gib);
    }

    // ---- encoder recurrence + concurrent dgi GEMM -------------------------
    enc_dgi_kernel<<<ENC_BLOCKS + DGI_TILES, 256, 0, stream>>>(
        wencp, bhhf, bhhb, gif, gib, lens, hbuf, flags, ysf, ysb, hfv, hbv,
        decinb, dwihb, dbih, dgi);
    packE_h0_kernel<<<B * (S / 32) + NB, 256, 0, stream>>>(
        ysf, ysb, Eb, ETb, hfv, hbv, hf32, hnk);

    // ---- decoder: dgh_0 + per-step {cell||rowsum(t-1), attn||dgh(t+1)} ----
    {
        dim3 g((NB + 63) / 64, (H3 + 63) / 64);
        gemm_bt<<<g, 256, 0, stream>>>(hnk, dwhhb, dbhh, dgh, NB, H3, H, H, H, H3);
    }
    for (int t = 0; t < T; ++t) {
        cell_rowsum_kernel<<<CELL_BLOCKS + RS_TILES, 256, 0, stream>>>(
            dgi, dgh, hf32, hall, embb, rowsumT, t);
        dec_attn_kernel<<<DGH_TILES + 16, 512, FUSED_LDS, stream>>>(
            hall, dwhhb, dbhh, dgh, decinb, embb, Eb, ETb, lens,
            Wr, br, Wg, bg, probfT, swvT, rowsumT,
            out + (size_t)NB * T * V, t);
    }

    // ---- vocab pass B (fused scale) + scatter -----------------------------
    {
        dim3 g((MM + 127) / 128, (V + 127) / 128);
        vocab_write_kernel<<<g, 256, 0, stream>>>(hall, embb, swvT, rowsumT, out);
    }
    { dim3 g(NB, T); scatter_all_kernel<<<g, 256, 0, stream>>>(out, story, lens, swvT, probfT); }
}

// Round 17
// 2348.830 us; speedup vs baseline: 1.0297x; 1.0297x over previous
//
#include <hip/hip_runtime.h>
#include <hip/hip_bf16.h>

typedef unsigned short u16;
typedef __attribute__((ext_vector_type(8))) short bf16x8;
typedef __attribute__((ext_vector_type(4))) float f32x4;
typedef __attribute__((ext_vector_type(4))) unsigned u32x4;

static constexpr int V = 20000, H = 400, B = 16, S = 256, NSLOT = 30, T = 10, G = 3;
static constexpr int H3 = 3 * H;           // 1200
static constexpr int NB = NSLOT * B;       // 480
static constexpr int MM = T * NB;          // 4800 vocab-GEMM rows
// encoder partition (R8 protocol — best measured)
static constexpr int ENBLK = 20;
static constexpr int ESL   = 20;
static constexpr int EROWS = 64;
static constexpr int EKP   = 416;
static constexpr int ENC_BLOCKS = 2 * ENBLK;               // 40
static constexpr int DGI_TM = (MM + 63) / 64;              // 75
static constexpr int DGI_TN = (H3 + 63) / 64;              // 19
static constexpr int DGI_TILES = DGI_TM * DGI_TN;          // 1425
// decoder dgh tiles (co-launched with attention)
static constexpr int DGH_TM = (NB + 63) / 64;              // 8
static constexpr int DGH_TN = (H3 + 63) / 64;              // 19
static constexpr int DGH_TILES = DGH_TM * DGH_TN;          // 152
// merged vocab pass A/B tiles
static constexpr int RSA_TM = (MM + 127) / 128;            // 38
static constexpr int RSA_TN = (V + 127) / 128;             // 157
static constexpr int RSA_TILES = RSA_TM * RSA_TN;          // 5966
// fused decoder LDS strides
static constexpr int HP2 = 424;
static constexpr int SCP = 260;
static constexpr int PP  = 264;
static constexpr int CXP = 404;
static constexpr int FUSED_LDS = 32*HP2*2 + 32*SCP*4 + 32*PP*2 + 32*CXP*4; // 129024
// prep_all segment sizes
static constexpr int NE = V * H;
static constexpr int NW = H3 * H;
static constexpr int NP = 2 * ENBLK * EROWS * EKP;

__device__ __forceinline__ float bf2f(u16 v) {
    union { unsigned u; float f; } x; x.u = ((unsigned)v) << 16; return x.f;
}
__device__ __forceinline__ u16 f2bf(float f) {
    union { float f; unsigned u; } x; x.f = f;
    unsigned r = x.u + 0x7fffu + ((x.u >> 16) & 1u);   // round-to-nearest-even
    return (u16)(r >> 16);
}
__device__ __forceinline__ float sigm(float v) { return 1.f / (1.f + __expf(-v)); }

// ---------------------------------------------------------------------------
// Generic GEMM (pre-loop dgh_0): C[m][n] = A.Bt^T + bias
// ---------------------------------------------------------------------------
__global__ __launch_bounds__(256) void gemm_bt(
    const u16* __restrict__ A, const u16* __restrict__ Bt,
    const float* __restrict__ bias, float* __restrict__ C,
    int M, int N, int K, int lda, int ldb, long long ldc)
{
    __shared__ u16 As[64][40];
    __shared__ u16 Bs[64][40];
    const int m0 = blockIdx.x * 64, n0 = blockIdx.y * 64;
    const int tid = threadIdx.x, wave = tid >> 6, lane = tid & 63;
    const int wm = (wave >> 1) * 32, wn = (wave & 1) * 32;
    const int srow = tid >> 2, scol = (tid & 3) * 8;
    const int fr = lane & 15, kq = lane >> 4;
    f32x4 acc[2][2];
#pragma unroll
    for (int i = 0; i < 2; ++i)
#pragma unroll
        for (int j = 0; j < 2; ++j) acc[i][j] = (f32x4){0.f, 0.f, 0.f, 0.f};

    for (int k0 = 0; k0 < K; k0 += 32) {
        {
            int gr = m0 + srow, gc = k0 + scol;
            bf16x8 v = (bf16x8){0,0,0,0,0,0,0,0};
            if (gr < M && gc + 8 <= K) v = *(const bf16x8*)(A + (long long)gr * lda + gc);
            *(bf16x8*)&As[srow][scol] = v;
        }
        {
            int gr = n0 + srow, gc = k0 + scol;
            bf16x8 v = (bf16x8){0,0,0,0,0,0,0,0};
            if (gr < N && gc + 8 <= K) v = *(const bf16x8*)(Bt + (long long)gr * ldb + gc);
            *(bf16x8*)&Bs[srow][scol] = v;
        }
        __syncthreads();
        bf16x8 af[2], bfr[2];
#pragma unroll
        for (int i = 0; i < 2; ++i) af[i]  = *(const bf16x8*)&As[wm + i * 16 + fr][kq * 8];
#pragma unroll
        for (int j = 0; j < 2; ++j) bfr[j] = *(const bf16x8*)&Bs[wn + j * 16 + fr][kq * 8];
#pragma unroll
        for (int i = 0; i < 2; ++i)
#pragma unroll
            for (int j = 0; j < 2; ++j)
                acc[i][j] = __builtin_amdgcn_mfma_f32_16x16x32_bf16(af[i], bfr[j], acc[i][j], 0, 0, 0);
        __syncthreads();
    }

#pragma unroll
    for (int i = 0; i < 2; ++i)
#pragma unroll
        for (int j = 0; j < 2; ++j) {
            int col = n0 + wn + j * 16 + fr;
            float bv = (bias != nullptr && col < N) ? bias[col] : 0.f;
#pragma unroll
            for (int r = 0; r < 4; ++r) {
                int row = m0 + wm + i * 16 + kq * 4 + r;
                if (row < M && col < N) C[(long long)row * ldc + col] = acc[i][j][r] + bv;
            }
        }
}

// ---------------------------------------------------------------------------
// gif + gib in ONE launch: blockIdx.z picks (W, bias, C). A = xb, M = S*B.
// ---------------------------------------------------------------------------
__global__ __launch_bounds__(256) void gemm_xw2_kernel(
    const u16* __restrict__ A,
    const u16* __restrict__ W0, const u16* __restrict__ W1,
    const float* __restrict__ b0, const float* __restrict__ b1,
    float* __restrict__ C0, float* __restrict__ C1)
{
    const int z = blockIdx.z;
    const u16* Bt = z ? W1 : W0;
    const float* bias = z ? b1 : b0;
    float* C = z ? C1 : C0;
    const int M = S * B, N = H3, K = H;

    __shared__ u16 As[64][40];
    __shared__ u16 Bs[64][40];
    const int m0 = blockIdx.x * 64, n0 = blockIdx.y * 64;
    const int tid = threadIdx.x, wave = tid >> 6, lane = tid & 63;
    const int wm = (wave >> 1) * 32, wn = (wave & 1) * 32;
    const int srow = tid >> 2, scol = (tid & 3) * 8;
    const int fr = lane & 15, kq = lane >> 4;
    f32x4 acc[2][2];
#pragma unroll
    for (int i = 0; i < 2; ++i)
#pragma unroll
        for (int j = 0; j < 2; ++j) acc[i][j] = (f32x4){0.f, 0.f, 0.f, 0.f};

    for (int k0 = 0; k0 < K; k0 += 32) {
        {
            int gr = m0 + srow, gc = k0 + scol;
            bf16x8 v = (bf16x8){0,0,0,0,0,0,0,0};
            if (gr < M && gc + 8 <= K) v = *(const bf16x8*)(A + (long long)gr * K + gc);
            *(bf16x8*)&As[srow][scol] = v;
        }
        {
            int gr = n0 + srow, gc = k0 + scol;
            bf16x8 v = (bf16x8){0,0,0,0,0,0,0,0};
            if (gr < N && gc + 8 <= K) v = *(const bf16x8*)(Bt + (long long)gr * K + gc);
            *(bf16x8*)&Bs[srow][scol] = v;
        }
        __syncthreads();
        bf16x8 af[2], bfr[2];
#pragma unroll
        for (int i = 0; i < 2; ++i) af[i]  = *(const bf16x8*)&As[wm + i * 16 + fr][kq * 8];
#pragma unroll
        for (int j = 0; j < 2; ++j) bfr[j] = *(const bf16x8*)&Bs[wn + j * 16 + fr][kq * 8];
#pragma unroll
        for (int i = 0; i < 2; ++i)
#pragma unroll
            for (int j = 0; j < 2; ++j)
                acc[i][j] = __builtin_amdgcn_mfma_f32_16x16x32_bf16(af[i], bfr[j], acc[i][j], 0, 0, 0);
        __syncthreads();
    }

#pragma unroll
    for (int i = 0; i < 2; ++i)
#pragma unroll
        for (int j = 0; j < 2; ++j) {
            int col = n0 + wn + j * 16 + fr;
            float bv = (col < N) ? bias[col] : 0.f;
#pragma unroll
            for (int r = 0; r < 4; ++r) {
                int row = m0 + wm + i * 16 + kq * 4 + r;
                if (row < M && col < N) C[(long long)row * H3 + col] = acc[i][j][r] + bv;
            }
        }
}

// ---------------------------------------------------------------------------
// Merged vocab pass A+B, one launch (R8-style producer->consumer):
//  blocks 0..RSA_TILES-1        : pass A (m-major) — exp+rowsum atomics,
//                                 __syncthreads (vmcnt drain), vcnt[m]++.
//  blocks RSA_TILES..2*RSA-1    : pass B (m-major) — poll vcnt[m]==RSA_TN
//                                 relaxed, then recompute tile and write
//                                 exp(acc)*sw/rowsum (rowsum: L2-cold read).
// A blocks are dispatched before B blocks (in-order dispatch) -> no deadlock.
// ---------------------------------------------------------------------------
__global__ __launch_bounds__(256) void vocab_ab_kernel(
    const u16* __restrict__ A, const u16* __restrict__ Bt,
    const float* __restrict__ swvT, float* __restrict__ rowsum,
    int* __restrict__ vcnt, float* __restrict__ C)
{
    __shared__ u16 As[128][40];
    __shared__ u16 Bs[128][40];
    const bool isA = blockIdx.x < RSA_TILES;
    const int tile = isA ? blockIdx.x : blockIdx.x - RSA_TILES;
    const int mb = tile / RSA_TN, nt = tile % RSA_TN;
    const int m0 = mb * 128, n0 = nt * 128;
    const int tid = threadIdx.x, wave = tid >> 6, lane = tid & 63;
    const int wm = (wave >> 1) * 64, wn = (wave & 1) * 64;
    const int srow = tid >> 1, scol = (tid & 1) * 16;
    const int fr = lane & 15, kq = lane >> 4;

    if (!isA) {
        // wait until all RSA_TN pass-A tiles of this row-block finished
        if (tid == 0) {
            while (__hip_atomic_load(&vcnt[mb], __ATOMIC_RELAXED,
                                     __HIP_MEMORY_SCOPE_AGENT) < RSA_TN)
                __builtin_amdgcn_s_sleep(4);
        }
        __syncthreads();
        asm volatile("" ::: "memory");   // keep rowsum reads after the poll
    }

    f32x4 acc[4][4];
#pragma unroll
    for (int i = 0; i < 4; ++i)
#pragma unroll
        for (int j = 0; j < 4; ++j) acc[i][j] = (f32x4){0.f, 0.f, 0.f, 0.f};

    for (int k0 = 0; k0 < H; k0 += 32) {
        {
            int gr = m0 + srow, gc = k0 + scol;
            bf16x8 v0 = (bf16x8){0,0,0,0,0,0,0,0}, v1 = v0;
            if (gr < MM) {
                const u16* src = A + (long long)gr * H + gc;
                if (gc + 8 <= H)  v0 = *(const bf16x8*)src;
                if (gc + 16 <= H) v1 = *(const bf16x8*)(src + 8);
            }
            *(bf16x8*)&As[srow][scol] = v0;
            *(bf16x8*)&As[srow][scol + 8] = v1;
        }
        {
            int gr = n0 + srow, gc = k0 + scol;
            bf16x8 v0 = (bf16x8){0,0,0,0,0,0,0,0}, v1 = v0;
            if (gr < V) {
                const u16* src = Bt + (long long)gr * H + gc;
                if (gc + 8 <= H)  v0 = *(const bf16x8*)src;
                if (gc + 16 <= H) v1 = *(const bf16x8*)(src + 8);
            }
            *(bf16x8*)&Bs[srow][scol] = v0;
            *(bf16x8*)&Bs[srow][scol + 8] = v1;
        }
        __syncthreads();
        bf16x8 af[4], bfr[4];
#pragma unroll
        for (int i = 0; i < 4; ++i) af[i]  = *(const bf16x8*)&As[wm + i * 16 + fr][kq * 8];
#pragma unroll
        for (int j = 0; j < 4; ++j) bfr[j] = *(const bf16x8*)&Bs[wn + j * 16 + fr][kq * 8];
#pragma unroll
        for (int i = 0; i < 4; ++i)
#pragma unroll
            for (int j = 0; j < 4; ++j)
                acc[i][j] = __builtin_amdgcn_mfma_f32_16x16x32_bf16(af[i], bfr[j], acc[i][j], 0, 0, 0);
        __syncthreads();
    }

    if (isA) {
#pragma unroll
        for (int i = 0; i < 4; ++i)
#pragma unroll
            for (int r = 0; r < 4; ++r) {
                int row = m0 + wm + i * 16 + kq * 4 + r;
                float s = 0.f;
#pragma unroll
                for (int j = 0; j < 4; ++j) {
                    int col = n0 + wn + j * 16 + fr;
                    if (row < MM && col < V) s += __expf(acc[i][j][r]);
                }
                s += __shfl_xor(s, 1); s += __shfl_xor(s, 2);
                s += __shfl_xor(s, 4); s += __shfl_xor(s, 8);
                if (fr == 0 && row < MM) atomicAdd(&rowsum[row], s);
            }
        // drain all waves' rowsum atomics (vmcnt0) before signalling
        __syncthreads();
        if (tid == 0)
            __hip_atomic_fetch_add(&vcnt[mb], 1, __ATOMIC_RELAXED,
                                   __HIP_MEMORY_SCOPE_AGENT);
    } else {
#pragma unroll
        for (int i = 0; i < 4; ++i)
#pragma unroll
            for (int r = 0; r < 4; ++r) {
                int row = m0 + wm + i * 16 + kq * 4 + r;
                float f = 0.f;
                if (row < MM) f = swvT[row] / rowsum[row];
#pragma unroll
                for (int j = 0; j < 4; ++j) {
                    int col = n0 + wn + j * 16 + fr;
                    if (row < MM && col < V) {
                        int n = row % NB, t = row / NB;
                        C[((long long)n * T + t) * V + col] = __expf(acc[i][j][r]) * f;
                    }
                }
            }
    }
}

// ---------------------------------------------------------------------------
// prep_all: emb cvt + 4 weight cvts + encoder weight prep, one grid-stride
// ---------------------------------------------------------------------------
__global__ void prep_all_kernel(
    const float* __restrict__ emb, u16* __restrict__ embb,
    const float* __restrict__ wihf, u16* __restrict__ wihfb,
    const float* __restrict__ wihb, u16* __restrict__ wihbb,
    const float* __restrict__ dwih, u16* __restrict__ dwihb,
    const float* __restrict__ dwhh, u16* __restrict__ dwhhb,
    const float* __restrict__ whhf, const float* __restrict__ whhb,
    u16* __restrict__ wencp)
{
    const int total = NE + 4 * NW + NP;
    for (int i = blockIdx.x * blockDim.x + threadIdx.x; i < total;
         i += gridDim.x * blockDim.x) {
        if (i < NE) { embb[i] = f2bf(emb[i]); continue; }
        int i2 = i - NE;
        if (i2 < NW) { wihfb[i2] = f2bf(wihf[i2]); continue; }
        i2 -= NW;
        if (i2 < NW) { wihbb[i2] = f2bf(wihb[i2]); continue; }
        i2 -= NW;
        if (i2 < NW) { dwihb[i2] = f2bf(dwih[i2]); continue; }
        i2 -= NW;
        if (i2 < NW) { dwhhb[i2] = f2bf(dwhh[i2]); continue; }
        i2 -= NW;
        int k = i2 % EKP; int r = i2 / EKP;
        int rloc = r % EROWS; r /= EROWS;
        int j = r % ENBLK; int dir = r / ENBLK;
        u16 v = 0;
        if (k < H && rloc < 3 * ESL) {
            int g = rloc / ESL, c = rloc % ESL;
            const float* W = dir ? whhb : whhf;
            v = f2bf(W[(long long)(g * H + j * ESL + c) * H + k]);
        }
        wencp[i2] = v;
    }
}

// embed_story + build_decin, one launch
__global__ void embed_decin_kernel(
    const int* __restrict__ story, const u16* __restrict__ embb,
    u16* __restrict__ xb,
    const int* __restrict__ tgt, const int* __restrict__ dom,
    const int* __restrict__ sidx, const float* __restrict__ slt,
    u16* __restrict__ decin)
{
    int row = blockIdx.x;
    if (row < S * B) {
        int s = row >> 4, b = row & 15;
        int tok = story[b * S + s];
        const u16* e = embb + (long long)tok * H;
        u16* d = xb + (long long)row * H;
        for (int k = threadIdx.x; k < H; k += blockDim.x) d[k] = e[k];
    } else {
        int i = row - S * B;
        int t = i / NB, n = i % NB;
        int b = n & 15, slot = n >> 4;
        u16* d = decin + ((long long)t * NB + n) * H;
        if (t == 0) {
            const float* s1 = slt + (long long)dom[slot] * H;
            const float* s2 = slt + (long long)sidx[slot] * H;
            for (int k = threadIdx.x; k < H; k += blockDim.x) d[k] = f2bf(s1[k] + s2[k]);
        } else {
            int tok = tgt[(b * NSLOT + slot) * T + (t - 1)];
            const u16* e = embb + (long long)tok * H;
            for (int k = threadIdx.x; k < H; k += blockDim.x) d[k] = e[k];
        }
    }
}

// ---------------------------------------------------------------------------
// Combined launch: blocks 0..39 = R8-protocol encoder; blocks 40.. = dgi
// GEMM tiles running concurrently on idle CUs. (R12, unchanged)
// ---------------------------------------------------------------------------
__global__ __launch_bounds__(256) void enc_dgi_kernel(
    const u16* __restrict__ wencp,
    const float* __restrict__ bhhf, const float* __restrict__ bhhb,
    const float* __restrict__ gif, const float* __restrict__ gib,
    const int* __restrict__ lens,
    unsigned* __restrict__ hbuf, int* __restrict__ flags,
    float* __restrict__ ysf, float* __restrict__ ysb,
    float* __restrict__ hfo, float* __restrict__ hbo,
    const u16* __restrict__ decinb, const u16* __restrict__ dwhib,
    const float* __restrict__ dbih, float* __restrict__ dgi)
{
    __shared__ __align__(16) char ldsu[EROWS * EKP * 2 + EROWS * 17 * 4];
    const int tid = threadIdx.x, wave = tid >> 6, lane = tid & 63;
    const int fr = lane & 15, kq = lane >> 4;

    if (blockIdx.x >= ENC_BLOCKS) {
        u16* As = (u16*)ldsu;
        u16* Bs = As + 64 * 40;
        const int tile = blockIdx.x - ENC_BLOCKS;
        const int m0 = (tile % DGI_TM) * 64, n0 = (tile / DGI_TM) * 64;
        const int wm = (wave >> 1) * 32, wn = (wave & 1) * 32;
        const int srow = tid >> 2, scol = (tid & 3) * 8;
        f32x4 acc[2][2];
#pragma unroll
        for (int i = 0; i < 2; ++i)
#pragma unroll
            for (int j = 0; j < 2; ++j) acc[i][j] = (f32x4){0.f, 0.f, 0.f, 0.f};

        for (int k0 = 0; k0 < H; k0 += 32) {
            {
                int gr = m0 + srow, gc = k0 + scol;
                bf16x8 v = (bf16x8){0,0,0,0,0,0,0,0};
                if (gr < MM && gc + 8 <= H) v = *(const bf16x8*)(decinb + (long long)gr * H + gc);
                *(bf16x8*)&As[srow * 40 + scol] = v;
            }
            {
                int gr = n0 + srow, gc = k0 + scol;
                bf16x8 v = (bf16x8){0,0,0,0,0,0,0,0};
                if (gr < H3 && gc + 8 <= H) v = *(const bf16x8*)(dwhib + (long long)gr * H + gc);
                *(bf16x8*)&Bs[srow * 40 + scol] = v;
            }
            __syncthreads();
            bf16x8 af[2], bfr[2];
#pragma unroll
            for (int i = 0; i < 2; ++i) af[i]  = *(const bf16x8*)&As[(wm + i * 16 + fr) * 40 + kq * 8];
#pragma unroll
            for (int j = 0; j < 2; ++j) bfr[j] = *(const bf16x8*)&Bs[(wn + j * 16 + fr) * 40 + kq * 8];
#pragma unroll
            for (int i = 0; i < 2; ++i)
#pragma unroll
                for (int j = 0; j < 2; ++j)
                    acc[i][j] = __builtin_amdgcn_mfma_f32_16x16x32_bf16(af[i], bfr[j], acc[i][j], 0, 0, 0);
            __syncthreads();
        }
#pragma unroll
        for (int i = 0; i < 2; ++i)
#pragma unroll
            for (int j = 0; j < 2; ++j) {
                int col = n0 + wn + j * 16 + fr;
                float bv = (col < H3) ? dbih[col] : 0.f;
#pragma unroll
                for (int r = 0; r < 4; ++r) {
                    int row = m0 + wm + i * 16 + kq * 4 + r;
                    if (row < MM && col < H3) dgi[(long long)row * H3 + col] = acc[i][j][r] + bv;
                }
            }
        return;
    }

    u16* wlds = (u16*)ldsu;
    float* ghs = (float*)(ldsu + EROWS * EKP * 2);
    const int bid = blockIdx.x;
    const int dir = bid / ENBLK, j = bid % ENBLK;
    const float* bhh = dir ? bhhb : bhhf;
    const float* gi  = dir ? gib  : gif;
    float* ys = dir ? ysb : ysf;
    float* ho = dir ? hbo : hfo;

    const u16* wsrc = wencp + (long long)(dir * ENBLK + j) * EROWS * EKP;
    for (int i = tid * 8; i < EROWS * EKP; i += 256 * 8)
        *(bf16x8*)&wlds[i] = *(const bf16x8*)&wsrc[i];
    for (int i = tid; i < EROWS * 17; i += 256) ghs[i] = 0.f;

    const int p0 = tid, p1 = 256 + tid;
    const bool has1 = (tid < 64);
    const int b0 = p0 / ESL, kl0 = p0 % ESL;
    const int b1 = has1 ? p1 / ESL : 0, kl1 = has1 ? p1 % ESL : 0;
    const int k0 = j * ESL;
    const int len0 = lens[b0];
    const int len1 = has1 ? lens[b1] : 0;
    const float bhr0 = bhh[k0 + kl0], bhz0 = bhh[H + k0 + kl0], bhn0 = bhh[2 * H + k0 + kl0];
    const float bhr1 = has1 ? bhh[k0 + kl1] : 0.f;
    const float bhz1 = has1 ? bhh[H + k0 + kl1] : 0.f;
    const float bhn1 = has1 ? bhh[2 * H + k0 + kl1] : 0.f;
    float h0r = 0.f, h1r = 0.f;

    unsigned* hb_d = hbuf + (long long)dir * S * B * EKP;
    int* flg_d = flags + dir * S * ENBLK;
    const u16* arow = &wlds[(wave * 16 + fr) * EKP + kq * 8];
    __syncthreads();

    for (int t = 0; t < S; ++t) {
        const int s = dir ? (S - 1 - t) : t;
        const float* gbase = gi + (long long)s * B * H3;
        float gr0 = gbase[b0 * H3 + k0 + kl0];
        float gz0 = gbase[b0 * H3 + H + k0 + kl0];
        float gn0 = gbase[b0 * H3 + 2 * H + k0 + kl0];
        float gr1 = 0.f, gz1 = 0.f, gn1 = 0.f;
        if (has1) {
            gr1 = gbase[b1 * H3 + k0 + kl1];
            gz1 = gbase[b1 * H3 + H + k0 + kl1];
            gn1 = gbase[b1 * H3 + 2 * H + k0 + kl1];
        }

        f32x4 acc = (f32x4){0.f, 0.f, 0.f, 0.f};
        if (t > 0) {
            const int* fl = flg_d + (t - 1) * ENBLK;
            for (;;) {
                int v = 1;
                if (lane < ENBLK)
                    v = __hip_atomic_load(&fl[lane], __ATOMIC_RELAXED,
                                          __HIP_MEMORY_SCOPE_AGENT);
                if (__all(v != 0)) break;
                __builtin_amdgcn_s_sleep(2);
            }
            asm volatile("" ::: "memory");
            const unsigned* hrow = hb_d + ((long long)(t - 1) * B + fr) * EKP + kq * 8;
            f32x4 acch = (f32x4){0.f, 0.f, 0.f, 0.f};
            f32x4 accl = (f32x4){0.f, 0.f, 0.f, 0.f};
#pragma unroll
            for (int kk = 0; kk < 13; ++kk) {
                u32x4 a = *(const u32x4*)(hrow + kk * 32);
                u32x4 b = *(const u32x4*)(hrow + kk * 32 + 4);
                union { unsigned u[4]; bf16x8 v; } hi, lo;
                hi.u[0] = __builtin_amdgcn_perm(a[1], a[0], 0x05040100u);
                hi.u[1] = __builtin_amdgcn_perm(a[3], a[2], 0x05040100u);
                hi.u[2] = __builtin_amdgcn_perm(b[1], b[0], 0x05040100u);
                hi.u[3] = __builtin_amdgcn_perm(b[3], b[2], 0x05040100u);
                lo.u[0] = __builtin_amdgcn_perm(a[1], a[0], 0x07060302u);
                lo.u[1] = __builtin_amdgcn_perm(a[3], a[2], 0x07060302u);
                lo.u[2] = __builtin_amdgcn_perm(b[1], b[0], 0x07060302u);
                lo.u[3] = __builtin_amdgcn_perm(b[3], b[2], 0x07060302u);
                bf16x8 av = *(const bf16x8*)(arow + kk * 32);
                acch = __builtin_amdgcn_mfma_f32_16x16x32_bf16(av, hi.v, acch, 0, 0, 0);
                accl = __builtin_amdgcn_mfma_f32_16x16x32_bf16(av, lo.v, accl, 0, 0, 0);
            }
            acc = acch + accl;
        }
#pragma unroll
        for (int r = 0; r < 4; ++r) ghs[(wave * 16 + kq * 4 + r) * 17 + fr] = acc[r];
        __syncthreads();

        unsigned* hpub = hb_d + (long long)t * B * EKP;
        {
            float ghr = ghs[kl0 * 17 + b0];
            float ghz = ghs[(ESL + kl0) * 17 + b0];
            float ghn = ghs[(2 * ESL + kl0) * 17 + b0];
            float rg = sigm(gr0 + ghr + bhr0);
            float zg = sigm(gz0 + ghz + bhz0);
            float ng = tanhf(gn0 + rg * (ghn + bhn0));
            float hn = (1.f - zg) * ng + zg * h0r;
            bool msk = s < len0;
            float y = msk ? hn : 0.f;
            if (msk) h0r = hn;
            ys[((long long)(b0 * S + s)) * H + k0 + kl0] = y;
            u16 hi = f2bf(h0r);
            unsigned packed = (unsigned)hi | ((unsigned)f2bf(h0r - bf2f(hi)) << 16);
            __hip_atomic_store(&hpub[b0 * EKP + k0 + kl0], packed, __ATOMIC_RELAXED,
                               __HIP_MEMORY_SCOPE_AGENT);
        }
        if (has1) {
            float ghr = ghs[kl1 * 17 + b1];
            float ghz = ghs[(ESL + kl1) * 17 + b1];
            float ghn = ghs[(2 * ESL + kl1) * 17 + b1];
            float rg = sigm(gr1 + ghr + bhr1);
            float zg = sigm(gz1 + ghz + bhz1);
            float ng = tanhf(gn1 + rg * (ghn + bhn1));
            float hn = (1.f - zg) * ng + zg * h1r;
            bool msk = s < len1;
            float y = msk ? hn : 0.f;
            if (msk) h1r = hn;
            ys[((long long)(b1 * S + s)) * H + k0 + kl1] = y;
            u16 hi = f2bf(h1r);
            unsigned packed = (unsigned)hi | ((unsigned)f2bf(h1r - bf2f(hi)) << 16);
            __hip_atomic_store(&hpub[b1 * EKP + k0 + kl1], packed, __ATOMIC_RELAXED,
                               __HIP_MEMORY_SCOPE_AGENT);
        }
        __syncthreads();
        if (tid == 0)
            __hip_atomic_store(&flg_d[t * ENBLK + j], 1, __ATOMIC_RELAXED,
                               __HIP_MEMORY_SCOPE_AGENT);
    }
    ho[b0 * H + k0 + kl0] = h0r;
    if (has1) ho[b1 * H + k0 + kl1] = h1r;
}

// packE + h0 merged: blocks 0..127 = packE tiles, 128..607 = h0 rows
__global__ __launch_bounds__(256) void packE_h0_kernel(
    const float* __restrict__ ysf, const float* __restrict__ ysb,
    u16* __restrict__ E, u16* __restrict__ ET,
    const float* __restrict__ hf, const float* __restrict__ hb,
    float* __restrict__ hf32, u16* __restrict__ hnk)
{
    __shared__ u16 tile[32][400];
    const int blk = blockIdx.x;
    if (blk < B * (S / 32)) {
        const int b = blk / (S / 32), s0 = (blk % (S / 32)) * 32;
        for (int si = 0; si < 32; ++si) {
            const long long base = ((long long)b * S + s0 + si) * H;
            for (int k = threadIdx.x; k < H; k += blockDim.x) {
                u16 v = f2bf(ysf[base + k] + ysb[base + k]);
                E[base + k] = v;
                tile[si][k] = v;
            }
        }
        __syncthreads();
        for (int idx = threadIdx.x; idx < 32 * H; idx += blockDim.x) {
            int k = idx >> 5, si = idx & 31;
            ET[((long long)b * H + k) * S + s0 + si] = tile[si][k];
        }
    } else {
        int n = blk - B * (S / 32), b = n & 15;
        for (int k = threadIdx.x; k < H; k += blockDim.x) {
            float v = hf[b * H + k] + hb[b * H + k];
            hf32[(long long)n * H + k] = v;
            hnk[(long long)n * H + k] = f2bf(v);
        }
    }
}

// ---------------------------------------------------------------------------
// A_t: GRU cell only. (R15 version)
// ---------------------------------------------------------------------------
__global__ __launch_bounds__(256) void gru_cell_kernel(
    const float* __restrict__ dgi, const float* __restrict__ dgh,
    float* __restrict__ hf32, u16* __restrict__ hall, int t)
{
    const int total = NB * H;
    for (int i = blockIdx.x * 256 + threadIdx.x; i < total; i += gridDim.x * 256) {
        int n = i / H, k = i % H;
        const float* gi = dgi + ((long long)t * NB + n) * H3;
        const float* gh = dgh + (long long)n * H3;
        float r  = sigm(gi[k] + gh[k]);
        float z  = sigm(gi[H + k] + gh[H + k]);
        float nn = tanhf(gi[2 * H + k] + r * gh[2 * H + k]);
        float h  = hf32[i];
        float hn = (1.f - z) * nn + z * h;
        hf32[i] = hn;
        hall[((long long)t * NB + n) * H + k] = f2bf(hn);
    }
}

// ---------------------------------------------------------------------------
// B_t: blocks 0..151 = dgh GEMM tiles for step t+1 (plain stores, consumed
// across the dispatch boundary); blocks 152..167 = attention for step t.
// (R15 version)
// ---------------------------------------------------------------------------
__global__ __launch_bounds__(512) void dec_attn_kernel(
    const u16* __restrict__ hall, const u16* __restrict__ dwhhb,
    const float* __restrict__ dbhh, float* __restrict__ dgh,
    const u16* __restrict__ decinb,
    const u16* __restrict__ Eb, const u16* __restrict__ ETb,
    const int* __restrict__ lens,
    const float* __restrict__ Wr, const float* __restrict__ br,
    const float* __restrict__ Wg, const float* __restrict__ bg,
    float* __restrict__ probfT, float* __restrict__ swvT,
    float* __restrict__ gout, int t)
{
    extern __shared__ char smem[];
    const int tid = threadIdx.x, wave = tid >> 6, lane = tid & 63;
    const int fr = lane & 15, kq = lane >> 4;
    const u16* hcur = hall + (long long)t * NB * H;

    if (blockIdx.x < DGH_TILES) {
        if (t == T - 1) return;            // no step t+1
        u16* As = (u16*)smem;              // [64][40]
        u16* Bs = As + 64 * 40;            // [64][40]
        const int tile = blockIdx.x;
        const int m0 = (tile % DGH_TM) * 64, n0 = (tile / DGH_TM) * 64;
        const bool act = (wave < 4);
        const int wm = (wave >> 1) * 32, wn = (wave & 1) * 32;
        const int srow = tid >> 2, scol = (tid & 3) * 8;
        f32x4 acc[2][2];
#pragma unroll
        for (int i = 0; i < 2; ++i)
#pragma unroll
            for (int j = 0; j < 2; ++j) acc[i][j] = (f32x4){0.f, 0.f, 0.f, 0.f};

        for (int k0 = 0; k0 < H; k0 += 32) {
            if (tid < 256) {
                {
                    int gr = m0 + srow, gc = k0 + scol;
                    bf16x8 v = (bf16x8){0,0,0,0,0,0,0,0};
                    if (gr < NB && gc + 8 <= H) v = *(const bf16x8*)(hcur + (long long)gr * H + gc);
                    *(bf16x8*)&As[srow * 40 + scol] = v;
                }
                {
                    int gr = n0 + srow, gc = k0 + scol;
                    bf16x8 v = (bf16x8){0,0,0,0,0,0,0,0};
                    if (gr < H3 && gc + 8 <= H) v = *(const bf16x8*)(dwhhb + (long long)gr * H + gc);
                    *(bf16x8*)&Bs[srow * 40 + scol] = v;
                }
            }
            __syncthreads();
            if (act) {
                bf16x8 af[2], bfr[2];
#pragma unroll
                for (int i = 0; i < 2; ++i) af[i]  = *(const bf16x8*)&As[(wm + i * 16 + fr) * 40 + kq * 8];
#pragma unroll
                for (int j = 0; j < 2; ++j) bfr[j] = *(const bf16x8*)&Bs[(wn + j * 16 + fr) * 40 + kq * 8];
#pragma unroll
                for (int i = 0; i < 2; ++i)
#pragma unroll
                    for (int j = 0; j < 2; ++j)
                        acc[i][j] = __builtin_amdgcn_mfma_f32_16x16x32_bf16(af[i], bfr[j], acc[i][j], 0, 0, 0);
            }
            __syncthreads();
        }
        if (act) {
#pragma unroll
            for (int i = 0; i < 2; ++i)
#pragma unroll
                for (int j = 0; j < 2; ++j) {
                    int col = n0 + wn + j * 16 + fr;
                    float bv = (col < H3) ? dbhh[col] : 0.f;
#pragma unroll
                    for (int r = 0; r < 4; ++r) {
                        int row = m0 + wm + i * 16 + kq * 4 + r;
                        if (row < NB && col < H3)
                            dgh[(long long)row * H3 + col] = acc[i][j][r] + bv;
                    }
                }
        }
        return;
    }

    // -------------------- attention role --------------------
    u16*   hls = (u16*)smem;                                   // [32][HP2]
    float* scs = (float*)(smem + 32 * HP2 * 2);                // [32][SCP]
    u16*   pls = (u16*)(smem + 32 * HP2 * 2 + 32 * SCP * 4);   // [32][PP]
    float* cxs = (float*)(smem + 32 * HP2 * 2 + 32 * SCP * 4 + 32 * PP * 2); // [32][CXP]

    const int b = blockIdx.x - DGH_TILES;
    const int len = lens[b];

    for (int i = tid; i < 32 * (HP2 - H); i += 512) {
        int r = i / (HP2 - H), c = H + i % (HP2 - H);
        hls[r * HP2 + c] = 0;
    }
    for (int i = tid; i < 2 * HP2; i += 512) hls[30 * HP2 + i] = 0;
    for (int i = tid; i < 2 * PP; i += 512) pls[30 * PP + i] = 0;

    for (int i = tid; i < 30 * H; i += 512) {
        int slot = i / H, k = i % H;
        hls[slot * HP2 + k] = hcur[((long long)(slot * 16 + b)) * H + k];
    }
    __syncthreads();

    // P1: scores
    {
        const int nt0 = wave * 2;
        f32x4 acc[2][2];
#pragma unroll
        for (int i = 0; i < 2; ++i)
#pragma unroll
            for (int jj = 0; jj < 2; ++jj) acc[i][jj] = (f32x4){0.f, 0.f, 0.f, 0.f};
        const u16* br0 = Eb + ((long long)b * S + nt0 * 16 + fr) * H + kq * 8;
        const u16* br1 = Eb + ((long long)b * S + (nt0 + 1) * 16 + fr) * H + kq * 8;
        const u16* ar0 = hls + fr * HP2 + kq * 8;
        const u16* ar1 = hls + (16 + fr) * HP2 + kq * 8;
#pragma unroll
        for (int kk = 0; kk < 13; ++kk) {
            bf16x8 av0 = *(const bf16x8*)(ar0 + kk * 32);
            bf16x8 av1 = *(const bf16x8*)(ar1 + kk * 32);
            bf16x8 bv0, bv1;
            if (kk == 12 && kq >= 2) {
                bv0 = (bf16x8){0,0,0,0,0,0,0,0}; bv1 = bv0;
            } else {
                bv0 = *(const bf16x8*)(br0 + kk * 32);
                bv1 = *(const bf16x8*)(br1 + kk * 32);
            }
            acc[0][0] = __builtin_amdgcn_mfma_f32_16x16x32_bf16(av0, bv0, acc[0][0], 0, 0, 0);
            acc[1][0] = __builtin_amdgcn_mfma_f32_16x16x32_bf16(av1, bv0, acc[1][0], 0, 0, 0);
            acc[0][1] = __builtin_amdgcn_mfma_f32_16x16x32_bf16(av0, bv1, acc[0][1], 0, 0, 0);
            acc[1][1] = __builtin_amdgcn_mfma_f32_16x16x32_bf16(av1, bv1, acc[1][1], 0, 0, 0);
        }
#pragma unroll
        for (int i = 0; i < 2; ++i)
#pragma unroll
            for (int jj = 0; jj < 2; ++jj)
#pragma unroll
                for (int r = 0; r < 4; ++r)
                    scs[(i * 16 + kq * 4 + r) * SCP + (nt0 + jj) * 16 + fr] = acc[i][jj][r];
    }
    __syncthreads();

    // P2: softmax
    for (int i = 0; i < 4; ++i) {
        int row = wave * 4 + i;
        if (row >= 30) break;
        int n = row * 16 + b;
        float v[4];
        float mx = -3.0e38f;
#pragma unroll
        for (int q = 0; q < 4; ++q) {
            int s = lane + 64 * q;
            float x = (s < len) ? scs[row * SCP + s] : -3.0e38f;
            v[q] = x; mx = fmaxf(mx, x);
        }
        mx = fmaxf(mx, __shfl_xor(mx, 1));  mx = fmaxf(mx, __shfl_xor(mx, 2));
        mx = fmaxf(mx, __shfl_xor(mx, 4));  mx = fmaxf(mx, __shfl_xor(mx, 8));
        mx = fmaxf(mx, __shfl_xor(mx, 16)); mx = fmaxf(mx, __shfl_xor(mx, 32));
        float sum = 0.f;
#pragma unroll
        for (int q = 0; q < 4; ++q) {
            int s = lane + 64 * q;
            float e = (s < len) ? __expf(v[q] - mx) : 0.f;
            v[q] = e; sum += e;
        }
        sum += __shfl_xor(sum, 1);  sum += __shfl_xor(sum, 2);
        sum += __shfl_xor(sum, 4);  sum += __shfl_xor(sum, 8);
        sum += __shfl_xor(sum, 16); sum += __shfl_xor(sum, 32);
        float inv = 1.f / sum;
#pragma unroll
        for (int q = 0; q < 4; ++q) {
            int s = lane + 64 * q;
            float pr = v[q] * inv;
            pls[row * PP + s] = f2bf(pr);
            probfT[((long long)(t * NB + n)) * S + s] = pr;
        }
    }
    __syncthreads();

    // P3: ctx
    for (int nt = wave; nt < 25; nt += 8) {
        f32x4 acc0 = (f32x4){0.f,0.f,0.f,0.f}, acc1 = (f32x4){0.f,0.f,0.f,0.f};
        const u16* brow = ETb + ((long long)b * H + nt * 16 + fr) * S + kq * 8;
        const u16* ar0 = pls + fr * PP + kq * 8;
        const u16* ar1 = pls + (16 + fr) * PP + kq * 8;
#pragma unroll
        for (int kk = 0; kk < 8; ++kk) {
            bf16x8 bv  = *(const bf16x8*)(brow + kk * 32);
            bf16x8 av0 = *(const bf16x8*)(ar0 + kk * 32);
            bf16x8 av1 = *(const bf16x8*)(ar1 + kk * 32);
            acc0 = __builtin_amdgcn_mfma_f32_16x16x32_bf16(av0, bv, acc0, 0, 0, 0);
            acc1 = __builtin_amdgcn_mfma_f32_16x16x32_bf16(av1, bv, acc1, 0, 0, 0);
        }
#pragma unroll
        for (int r = 0; r < 4; ++r) {
            cxs[(kq * 4 + r) * CXP + nt * 16 + fr] = acc0[r];
            cxs[(16 + kq * 4 + r) * CXP + nt * 16 + fr] = acc1[r];
        }
    }
    __syncthreads();

    // P4: p_gen (+ gate at t==0)
    for (int i = 0; i < 4; ++i) {
        int slot = wave + 8 * i;
        if (slot >= 30) break;
        int n = slot * 16 + b;
        const u16* xrow = decinb + ((long long)t * NB + n) * H;
        float p = 0.f;
        for (int k = lane; k < H; k += 64)
            p += bf2f(hls[slot * HP2 + k]) * Wr[k]
               + cxs[slot * CXP + k] * Wr[H + k]
               + bf2f(xrow[k]) * Wr[2 * H + k];
        p += __shfl_xor(p, 1);  p += __shfl_xor(p, 2);
        p += __shfl_xor(p, 4);  p += __shfl_xor(p, 8);
        p += __shfl_xor(p, 16); p += __shfl_xor(p, 32);
        if (lane == 0) swvT[t * NB + n] = sigm(p + br[0]);
        if (t == 0) {
            for (int g = 0; g < G; ++g) {
                float q = 0.f;
                for (int k = lane; k < H; k += 64)
                    q += cxs[slot * CXP + k] * Wg[g * H + k];
                q += __shfl_xor(q, 1);  q += __shfl_xor(q, 2);
                q += __shfl_xor(q, 4);  q += __shfl_xor(q, 8);
                q += __shfl_xor(q, 16); q += __shfl_xor(q, 32);
                if (lane == 0) gout[(long long)n * G + g] = q + bg[g];
            }
        }
    }
}

__global__ void scatter_all_kernel(float* __restrict__ out, const int* __restrict__ story,
                                   const int* __restrict__ lens, const float* __restrict__ swvT,
                                   const float* __restrict__ probfT) {
    const int n = blockIdx.x, t = blockIdx.y, b = n & 15, s = threadIdx.x;
    if (s < lens[b]) {
        int tok = story[b * S + s];
        atomicAdd(out + ((long long)n * T + t) * V + tok,
                  (1.f - swvT[t * NB + n]) * probfT[((long long)(t * NB + n)) * S + s]);
    }
}

// ---------------------------------------------------------------------------
extern "C" void kernel_launch(void* const* d_in, const int* in_sizes, int n_in,
                              void* d_out, int out_size, void* d_ws, size_t ws_size,
                              hipStream_t stream) {
    const int*   story = (const int*)d_in[0];
    const int*   lens  = (const int*)d_in[1];
    const int*   tgt   = (const int*)d_in[2];
    const int*   dom   = (const int*)d_in[3];
    const int*   sidx  = (const int*)d_in[4];
    const float* emb   = (const float*)d_in[5];
    const float* wihf  = (const float*)d_in[6];
    const float* whhf  = (const float*)d_in[7];
    const float* bihf  = (const float*)d_in[8];
    const float* bhhf  = (const float*)d_in[9];
    const float* wihb  = (const float*)d_in[10];
    const float* whhb  = (const float*)d_in[11];
    const float* bihb  = (const float*)d_in[12];
    const float* bhhb  = (const float*)d_in[13];
    const float* dwih  = (const float*)d_in[14];
    const float* dwhh  = (const float*)d_in[15];
    const float* dbih  = (const float*)d_in[16];
    const float* dbhh  = (const float*)d_in[17];
    const float* Wr    = (const float*)d_in[18];
    const float* br    = (const float*)d_in[19];
    const float* Wg    = (const float*)d_in[20];
    const float* bg    = (const float*)d_in[21];
    const float* slt   = (const float*)d_in[22];
    float* out = (float*)d_out;

    char* wsb = (char*)d_ws;
    size_t off = 0;
    auto alloc = [&](size_t bytes) -> char* {
        char* p = wsb + off;
        off += (bytes + 255) & ~(size_t)255;
        return p;
    };
    u16*   embb   = (u16*)alloc((size_t)V * H * 2);
    u16*   wihfb  = (u16*)alloc((size_t)H3 * H * 2);
    u16*   wihbb  = (u16*)alloc((size_t)H3 * H * 2);
    u16*   dwihb  = (u16*)alloc((size_t)H3 * H * 2);
    u16*   dwhhb  = (u16*)alloc((size_t)H3 * H * 2);
    u16*   wencp  = (u16*)alloc((size_t)2 * ENBLK * EROWS * EKP * 2);
    unsigned* hbuf = (unsigned*)alloc((size_t)2 * S * B * EKP * 4);
    int*   flags  = (int*)alloc((size_t)2 * S * ENBLK * 4);
    u16*   xb     = (u16*)alloc((size_t)S * B * H * 2);
    u16*   decinb = (u16*)alloc((size_t)T * NB * H * 2);
    float* gif    = (float*)alloc((size_t)S * B * H3 * 4);
    float* gib    = (float*)alloc((size_t)S * B * H3 * 4);
    float* dgi    = (float*)alloc((size_t)T * NB * H3 * 4);
    float* ysf    = (float*)alloc((size_t)B * S * H * 4);
    float* ysb    = (float*)alloc((size_t)B * S * H * 4);
    float* hfv    = (float*)alloc((size_t)B * H * 4);
    float* hbv    = (float*)alloc((size_t)B * H * 4);
    u16*   Eb     = (u16*)alloc((size_t)B * S * H * 2);
    u16*   ETb    = (u16*)alloc((size_t)B * H * S * 2);
    float* hf32   = (float*)alloc((size_t)NB * H * 4);
    u16*   hnk    = (u16*)alloc((size_t)NB * H * 2);
    u16*   hall   = (u16*)alloc((size_t)T * NB * H * 2);
    float* dgh    = (float*)alloc((size_t)NB * H3 * 4);
    float* probfT = (float*)alloc((size_t)T * NB * S * 4);
    float* swvT   = (float*)alloc((size_t)T * NB * 4);
    float* rowsumT = (float*)alloc((size_t)T * NB * 4);
    int*   vcnt   = (int*)alloc((size_t)RSA_TM * 4);
    (void)ws_size; (void)in_sizes; (void)n_in; (void)out_size;

    hipFuncSetAttribute((const void*)dec_attn_kernel,
                        hipFuncAttributeMaxDynamicSharedMemorySize, FUSED_LDS);

    // ---- setup ------------------------------------------------------------
    hipMemsetAsync(flags, 0, (size_t)2 * S * ENBLK * 4, stream);
    hipMemsetAsync(hbuf, 0, (size_t)2 * S * B * EKP * 4, stream);
    hipMemsetAsync(rowsumT, 0, (size_t)T * NB * 4, stream);
    hipMemsetAsync(vcnt, 0, (size_t)RSA_TM * 4, stream);
    prep_all_kernel<<<2048, 256, 0, stream>>>(emb, embb, wihf, wihfb, wihb, wihbb,
                                              dwih, dwihb, dwhh, dwhhb,
                                              whhf, whhb, wencp);
    embed_decin_kernel<<<S * B + T * NB, 256, 0, stream>>>(
        story, embb, xb, tgt, dom, sidx, slt, decinb);
    {
        dim3 g((S * B + 63) / 64, (H3 + 63) / 64, 2);
        gemm_xw2_kernel<<<g, 256, 0, stream>>>(xb, wihfb, wihbb, bihf, bihb, gif, gib);
    }

    // ---- encoder recurrence + concurrent dgi GEMM -------------------------
    enc_dgi_kernel<<<ENC_BLOCKS + DGI_TILES, 256, 0, stream>>>(
        wencp, bhhf, bhhb, gif, gib, lens, hbuf, flags, ysf, ysb, hfv, hbv,
        decinb, dwihb, dbih, dgi);
    packE_h0_kernel<<<B * (S / 32) + NB, 256, 0, stream>>>(
        ysf, ysb, Eb, ETb, hfv, hbv, hf32, hnk);

    // ---- decoder: dgh_0 + per-step {cell, attn || next-dgh} (R15) ---------
    {
        dim3 g((NB + 63) / 64, (H3 + 63) / 64);
        gemm_bt<<<g, 256, 0, stream>>>(hnk, dwhhb, dbhh, dgh, NB, H3, H, H, H, H3);
    }
    for (int t = 0; t < T; ++t) {
        gru_cell_kernel<<<750, 256, 0, stream>>>(dgi, dgh, hf32, hall, t);
        dec_attn_kernel<<<DGH_TILES + 16, 512, FUSED_LDS, stream>>>(
            hall, dwhhb, dbhh, dgh, decinb, Eb, ETb, lens,
            Wr, br, Wg, bg, probfT, swvT, out + (size_t)NB * T * V, t);
    }

    // ---- merged vocab pass A+B (producer->consumer, one launch) -----------
    vocab_ab_kernel<<<2 * RSA_TILES, 256, 0, stream>>>(
        hall, embb, swvT, rowsumT, vcnt, out);
    { dim3 g(NB, T); scatter_all_kernel<<<g, 256, 0, stream>>>(out, story, lens, swvT, probfT); }
}

// Round 18
// 2074.584 us; speedup vs baseline: 1.1658x; 1.1322x over previous
//
#include <hip/hip_runtime.h>
#include <hip/hip_bf16.h>

typedef unsigned short u16;
typedef __attribute__((ext_vector_type(8))) short bf16x8;
typedef __attribute__((ext_vector_type(4))) float f32x4;
typedef __attribute__((ext_vector_type(4))) unsigned u32x4;

static constexpr int V = 20000, H = 400, B = 16, S = 256, NSLOT = 30, T = 10, G = 3;
static constexpr int H3 = 3 * H;           // 1200
static constexpr int NB = NSLOT * B;       // 480
static constexpr int MM = T * NB;          // 4800 vocab-GEMM rows
// encoder partition (R8 protocol — best measured)
static constexpr int ENBLK = 20;
static constexpr int ESL   = 20;
static constexpr int EROWS = 64;
static constexpr int EKP   = 416;
static constexpr int ENC_BLOCKS = 2 * ENBLK;               // 40
static constexpr int DGI_TM = (MM + 63) / 64;              // 75
static constexpr int DGI_TN = (H3 + 63) / 64;              // 19
static constexpr int DGI_TILES = DGI_TM * DGI_TN;          // 1425
// decoder dgh tiles (co-launched with attention)
static constexpr int DGH_TM = (NB + 63) / 64;              // 8
static constexpr int DGH_TN = (H3 + 63) / 64;              // 19
static constexpr int DGH_TILES = DGH_TM * DGH_TN;          // 152
// fused decoder LDS strides
static constexpr int HP2 = 424;
static constexpr int SCP = 260;
static constexpr int PP  = 264;
static constexpr int CXP = 404;
static constexpr int FUSED_LDS = 32*HP2*2 + 32*SCP*4 + 32*PP*2 + 32*CXP*4; // 129024
// prep_all segment sizes
static constexpr int NE = V * H;
static constexpr int NW = H3 * H;
static constexpr int NP = 2 * ENBLK * EROWS * EKP;

__device__ __forceinline__ float bf2f(u16 v) {
    union { unsigned u; float f; } x; x.u = ((unsigned)v) << 16; return x.f;
}
__device__ __forceinline__ u16 f2bf(float f) {
    union { float f; unsigned u; } x; x.f = f;
    unsigned r = x.u + 0x7fffu + ((x.u >> 16) & 1u);   // round-to-nearest-even
    return (u16)(r >> 16);
}
__device__ __forceinline__ float sigm(float v) { return 1.f / (1.f + __expf(-v)); }

// ---------------------------------------------------------------------------
// Generic GEMM (pre-loop dgh_0): C[m][n] = A.Bt^T + bias
// ---------------------------------------------------------------------------
__global__ __launch_bounds__(256) void gemm_bt(
    const u16* __restrict__ A, const u16* __restrict__ Bt,
    const float* __restrict__ bias, float* __restrict__ C,
    int M, int N, int K, int lda, int ldb, long long ldc)
{
    __shared__ u16 As[64][40];
    __shared__ u16 Bs[64][40];
    const int m0 = blockIdx.x * 64, n0 = blockIdx.y * 64;
    const int tid = threadIdx.x, wave = tid >> 6, lane = tid & 63;
    const int wm = (wave >> 1) * 32, wn = (wave & 1) * 32;
    const int srow = tid >> 2, scol = (tid & 3) * 8;
    const int fr = lane & 15, kq = lane >> 4;
    f32x4 acc[2][2];
#pragma unroll
    for (int i = 0; i < 2; ++i)
#pragma unroll
        for (int j = 0; j < 2; ++j) acc[i][j] = (f32x4){0.f, 0.f, 0.f, 0.f};

    for (int k0 = 0; k0 < K; k0 += 32) {
        {
            int gr = m0 + srow, gc = k0 + scol;
            bf16x8 v = (bf16x8){0,0,0,0,0,0,0,0};
            if (gr < M && gc + 8 <= K) v = *(const bf16x8*)(A + (long long)gr * lda + gc);
            *(bf16x8*)&As[srow][scol] = v;
        }
        {
            int gr = n0 + srow, gc = k0 + scol;
            bf16x8 v = (bf16x8){0,0,0,0,0,0,0,0};
            if (gr < N && gc + 8 <= K) v = *(const bf16x8*)(Bt + (long long)gr * ldb + gc);
            *(bf16x8*)&Bs[srow][scol] = v;
        }
        __syncthreads();
        bf16x8 af[2], bfr[2];
#pragma unroll
        for (int i = 0; i < 2; ++i) af[i]  = *(const bf16x8*)&As[wm + i * 16 + fr][kq * 8];
#pragma unroll
        for (int j = 0; j < 2; ++j) bfr[j] = *(const bf16x8*)&Bs[wn + j * 16 + fr][kq * 8];
#pragma unroll
        for (int i = 0; i < 2; ++i)
#pragma unroll
            for (int j = 0; j < 2; ++j)
                acc[i][j] = __builtin_amdgcn_mfma_f32_16x16x32_bf16(af[i], bfr[j], acc[i][j], 0, 0, 0);
        __syncthreads();
    }

#pragma unroll
    for (int i = 0; i < 2; ++i)
#pragma unroll
        for (int j = 0; j < 2; ++j) {
            int col = n0 + wn + j * 16 + fr;
            float bv = (bias != nullptr && col < N) ? bias[col] : 0.f;
#pragma unroll
            for (int r = 0; r < 4; ++r) {
                int row = m0 + wm + i * 16 + kq * 4 + r;
                if (row < M && col < N) C[(long long)row * ldc + col] = acc[i][j][r] + bv;
            }
        }
}

// ---------------------------------------------------------------------------
// gif + gib in ONE launch: blockIdx.z picks (W, bias, C). A = xb, M = S*B.
// ---------------------------------------------------------------------------
__global__ __launch_bounds__(256) void gemm_xw2_kernel(
    const u16* __restrict__ A,
    const u16* __restrict__ W0, const u16* __restrict__ W1,
    const float* __restrict__ b0, const float* __restrict__ b1,
    float* __restrict__ C0, float* __restrict__ C1)
{
    const int z = blockIdx.z;
    const u16* Bt = z ? W1 : W0;
    const float* bias = z ? b1 : b0;
    float* C = z ? C1 : C0;
    const int M = S * B, N = H3, K = H;

    __shared__ u16 As[64][40];
    __shared__ u16 Bs[64][40];
    const int m0 = blockIdx.x * 64, n0 = blockIdx.y * 64;
    const int tid = threadIdx.x, wave = tid >> 6, lane = tid & 63;
    const int wm = (wave >> 1) * 32, wn = (wave & 1) * 32;
    const int srow = tid >> 2, scol = (tid & 3) * 8;
    const int fr = lane & 15, kq = lane >> 4;
    f32x4 acc[2][2];
#pragma unroll
    for (int i = 0; i < 2; ++i)
#pragma unroll
        for (int j = 0; j < 2; ++j) acc[i][j] = (f32x4){0.f, 0.f, 0.f, 0.f};

    for (int k0 = 0; k0 < K; k0 += 32) {
        {
            int gr = m0 + srow, gc = k0 + scol;
            bf16x8 v = (bf16x8){0,0,0,0,0,0,0,0};
            if (gr < M && gc + 8 <= K) v = *(const bf16x8*)(A + (long long)gr * K + gc);
            *(bf16x8*)&As[srow][scol] = v;
        }
        {
            int gr = n0 + srow, gc = k0 + scol;
            bf16x8 v = (bf16x8){0,0,0,0,0,0,0,0};
            if (gr < N && gc + 8 <= K) v = *(const bf16x8*)(Bt + (long long)gr * K + gc);
            *(bf16x8*)&Bs[srow][scol] = v;
        }
        __syncthreads();
        bf16x8 af[2], bfr[2];
#pragma unroll
        for (int i = 0; i < 2; ++i) af[i]  = *(const bf16x8*)&As[wm + i * 16 + fr][kq * 8];
#pragma unroll
        for (int j = 0; j < 2; ++j) bfr[j] = *(const bf16x8*)&Bs[wn + j * 16 + fr][kq * 8];
#pragma unroll
        for (int i = 0; i < 2; ++i)
#pragma unroll
            for (int j = 0; j < 2; ++j)
                acc[i][j] = __builtin_amdgcn_mfma_f32_16x16x32_bf16(af[i], bfr[j], acc[i][j], 0, 0, 0);
        __syncthreads();
    }

#pragma unroll
    for (int i = 0; i < 2; ++i)
#pragma unroll
        for (int j = 0; j < 2; ++j) {
            int col = n0 + wn + j * 16 + fr;
            float bv = (col < N) ? bias[col] : 0.f;
#pragma unroll
            for (int r = 0; r < 4; ++r) {
                int row = m0 + wm + i * 16 + kq * 4 + r;
                if (row < M && col < N) C[(long long)row * H3 + col] = acc[i][j][r] + bv;
            }
        }
}

// ---------------------------------------------------------------------------
// Vocab pass A: 128x128 tiles, NO C write — only exp + rowsum atomics.
// ---------------------------------------------------------------------------
__global__ __launch_bounds__(256) void vocab_rowsum_kernel(
    const u16* __restrict__ A, const u16* __restrict__ Bt,
    float* __restrict__ rowsum)
{
    __shared__ u16 As[128][40];
    __shared__ u16 Bs[128][40];
    const int m0 = blockIdx.x * 128, n0 = blockIdx.y * 128;
    const int tid = threadIdx.x, wave = tid >> 6, lane = tid & 63;
    const int wm = (wave >> 1) * 64, wn = (wave & 1) * 64;
    const int srow = tid >> 1, scol = (tid & 1) * 16;
    const int fr = lane & 15, kq = lane >> 4;
    f32x4 acc[4][4];
#pragma unroll
    for (int i = 0; i < 4; ++i)
#pragma unroll
        for (int j = 0; j < 4; ++j) acc[i][j] = (f32x4){0.f, 0.f, 0.f, 0.f};

    for (int k0 = 0; k0 < H; k0 += 32) {
        {
            int gr = m0 + srow, gc = k0 + scol;
            bf16x8 v0 = (bf16x8){0,0,0,0,0,0,0,0}, v1 = v0;
            if (gr < MM) {
                const u16* src = A + (long long)gr * H + gc;
                if (gc + 8 <= H)  v0 = *(const bf16x8*)src;
                if (gc + 16 <= H) v1 = *(const bf16x8*)(src + 8);
            }
            *(bf16x8*)&As[srow][scol] = v0;
            *(bf16x8*)&As[srow][scol + 8] = v1;
        }
        {
            int gr = n0 + srow, gc = k0 + scol;
            bf16x8 v0 = (bf16x8){0,0,0,0,0,0,0,0}, v1 = v0;
            if (gr < V) {
                const u16* src = Bt + (long long)gr * H + gc;
                if (gc + 8 <= H)  v0 = *(const bf16x8*)src;
                if (gc + 16 <= H) v1 = *(const bf16x8*)(src + 8);
            }
            *(bf16x8*)&Bs[srow][scol] = v0;
            *(bf16x8*)&Bs[srow][scol + 8] = v1;
        }
        __syncthreads();
        bf16x8 af[4], bfr[4];
#pragma unroll
        for (int i = 0; i < 4; ++i) af[i]  = *(const bf16x8*)&As[wm + i * 16 + fr][kq * 8];
#pragma unroll
        for (int j = 0; j < 4; ++j) bfr[j] = *(const bf16x8*)&Bs[wn + j * 16 + fr][kq * 8];
#pragma unroll
        for (int i = 0; i < 4; ++i)
#pragma unroll
            for (int j = 0; j < 4; ++j)
                acc[i][j] = __builtin_amdgcn_mfma_f32_16x16x32_bf16(af[i], bfr[j], acc[i][j], 0, 0, 0);
        __syncthreads();
    }

#pragma unroll
    for (int i = 0; i < 4; ++i)
#pragma unroll
        for (int r = 0; r < 4; ++r) {
            int row = m0 + wm + i * 16 + kq * 4 + r;
            float s = 0.f;
#pragma unroll
            for (int j = 0; j < 4; ++j) {
                int col = n0 + wn + j * 16 + fr;
                if (row < MM && col < V) s += __expf(acc[i][j][r]);
            }
            s += __shfl_xor(s, 1); s += __shfl_xor(s, 2);
            s += __shfl_xor(s, 4); s += __shfl_xor(s, 8);
            if (fr == 0 && row < MM) atomicAdd(&rowsum[row], s);
        }
}

// ---------------------------------------------------------------------------
// Vocab pass B: recompute tile, write FINAL value exp(acc)*sw/rowsum.
// ---------------------------------------------------------------------------
__global__ __launch_bounds__(256) void vocab_write_kernel(
    const u16* __restrict__ A, const u16* __restrict__ Bt,
    const float* __restrict__ swvT, const float* __restrict__ rowsum,
    float* __restrict__ C)
{
    __shared__ u16 As[128][40];
    __shared__ u16 Bs[128][40];
    const int m0 = blockIdx.x * 128, n0 = blockIdx.y * 128;
    const int tid = threadIdx.x, wave = tid >> 6, lane = tid & 63;
    const int wm = (wave >> 1) * 64, wn = (wave & 1) * 64;
    const int srow = tid >> 1, scol = (tid & 1) * 16;
    const int fr = lane & 15, kq = lane >> 4;
    f32x4 acc[4][4];
#pragma unroll
    for (int i = 0; i < 4; ++i)
#pragma unroll
        for (int j = 0; j < 4; ++j) acc[i][j] = (f32x4){0.f, 0.f, 0.f, 0.f};

    for (int k0 = 0; k0 < H; k0 += 32) {
        {
            int gr = m0 + srow, gc = k0 + scol;
            bf16x8 v0 = (bf16x8){0,0,0,0,0,0,0,0}, v1 = v0;
            if (gr < MM) {
                const u16* src = A + (long long)gr * H + gc;
                if (gc + 8 <= H)  v0 = *(const bf16x8*)src;
                if (gc + 16 <= H) v1 = *(const bf16x8*)(src + 8);
            }
            *(bf16x8*)&As[srow][scol] = v0;
            *(bf16x8*)&As[srow][scol + 8] = v1;
        }
        {
            int gr = n0 + srow, gc = k0 + scol;
            bf16x8 v0 = (bf16x8){0,0,0,0,0,0,0,0}, v1 = v0;
            if (gr < V) {
                const u16* src = Bt + (long long)gr * H + gc;
                if (gc + 8 <= H)  v0 = *(const bf16x8*)src;
                if (gc + 16 <= H) v1 = *(const bf16x8*)(src + 8);
            }
            *(bf16x8*)&Bs[srow][scol] = v0;
            *(bf16x8*)&Bs[srow][scol + 8] = v1;
        }
        __syncthreads();
        bf16x8 af[4], bfr[4];
#pragma unroll
        for (int i = 0; i < 4; ++i) af[i]  = *(const bf16x8*)&As[wm + i * 16 + fr][kq * 8];
#pragma unroll
        for (int j = 0; j < 4; ++j) bfr[j] = *(const bf16x8*)&Bs[wn + j * 16 + fr][kq * 8];
#pragma unroll
        for (int i = 0; i < 4; ++i)
#pragma unroll
            for (int j = 0; j < 4; ++j)
                acc[i][j] = __builtin_amdgcn_mfma_f32_16x16x32_bf16(af[i], bfr[j], acc[i][j], 0, 0, 0);
        __syncthreads();
    }

#pragma unroll
    for (int i = 0; i < 4; ++i)
#pragma unroll
        for (int r = 0; r < 4; ++r) {
            int row = m0 + wm + i * 16 + kq * 4 + r;
            float f = 0.f;
            if (row < MM) f = swvT[row] / rowsum[row];
#pragma unroll
            for (int j = 0; j < 4; ++j) {
                int col = n0 + wn + j * 16 + fr;
                if (row < MM && col < V) {
                    int n = row % NB, t = row / NB;
                    C[((long long)n * T + t) * V + col] = __expf(acc[i][j][r]) * f;
                }
            }
        }
}

// ---------------------------------------------------------------------------
// prep_all: emb cvt + 4 weight cvts + encoder weight prep, one grid-stride
// ---------------------------------------------------------------------------
__global__ void prep_all_kernel(
    const float* __restrict__ emb, u16* __restrict__ embb,
    const float* __restrict__ wihf, u16* __restrict__ wihfb,
    const float* __restrict__ wihb, u16* __restrict__ wihbb,
    const float* __restrict__ dwih, u16* __restrict__ dwihb,
    const float* __restrict__ dwhh, u16* __restrict__ dwhhb,
    const float* __restrict__ whhf, const float* __restrict__ whhb,
    u16* __restrict__ wencp)
{
    const int total = NE + 4 * NW + NP;
    for (int i = blockIdx.x * blockDim.x + threadIdx.x; i < total;
         i += gridDim.x * blockDim.x) {
        if (i < NE) { embb[i] = f2bf(emb[i]); continue; }
        int i2 = i - NE;
        if (i2 < NW) { wihfb[i2] = f2bf(wihf[i2]); continue; }
        i2 -= NW;
        if (i2 < NW) { wihbb[i2] = f2bf(wihb[i2]); continue; }
        i2 -= NW;
        if (i2 < NW) { dwihb[i2] = f2bf(dwih[i2]); continue; }
        i2 -= NW;
        if (i2 < NW) { dwhhb[i2] = f2bf(dwhh[i2]); continue; }
        i2 -= NW;
        int k = i2 % EKP; int r = i2 / EKP;
        int rloc = r % EROWS; r /= EROWS;
        int j = r % ENBLK; int dir = r / ENBLK;
        u16 v = 0;
        if (k < H && rloc < 3 * ESL) {
            int g = rloc / ESL, c = rloc % ESL;
            const float* W = dir ? whhb : whhf;
            v = f2bf(W[(long long)(g * H + j * ESL + c) * H + k]);
        }
        wencp[i2] = v;
    }
}

// embed_story + build_decin, one launch
__global__ void embed_decin_kernel(
    const int* __restrict__ story, const u16* __restrict__ embb,
    u16* __restrict__ xb,
    const int* __restrict__ tgt, const int* __restrict__ dom,
    const int* __restrict__ sidx, const float* __restrict__ slt,
    u16* __restrict__ decin)
{
    int row = blockIdx.x;
    if (row < S * B) {
        int s = row >> 4, b = row & 15;
        int tok = story[b * S + s];
        const u16* e = embb + (long long)tok * H;
        u16* d = xb + (long long)row * H;
        for (int k = threadIdx.x; k < H; k += blockDim.x) d[k] = e[k];
    } else {
        int i = row - S * B;
        int t = i / NB, n = i % NB;
        int b = n & 15, slot = n >> 4;
        u16* d = decin + ((long long)t * NB + n) * H;
        if (t == 0) {
            const float* s1 = slt + (long long)dom[slot] * H;
            const float* s2 = slt + (long long)sidx[slot] * H;
            for (int k = threadIdx.x; k < H; k += blockDim.x) d[k] = f2bf(s1[k] + s2[k]);
        } else {
            int tok = tgt[(b * NSLOT + slot) * T + (t - 1)];
            const u16* e = embb + (long long)tok * H;
            for (int k = threadIdx.x; k < H; k += blockDim.x) d[k] = e[k];
        }
    }
}

// ---------------------------------------------------------------------------
// Combined launch: blocks 0..39 = R8-protocol encoder; blocks 40.. = dgi
// GEMM tiles running concurrently on idle CUs. (R12, unchanged)
// ---------------------------------------------------------------------------
__global__ __launch_bounds__(256) void enc_dgi_kernel(
    const u16* __restrict__ wencp,
    const float* __restrict__ bhhf, const float* __restrict__ bhhb,
    const float* __restrict__ gif, const float* __restrict__ gib,
    const int* __restrict__ lens,
    unsigned* __restrict__ hbuf, int* __restrict__ flags,
    float* __restrict__ ysf, float* __restrict__ ysb,
    float* __restrict__ hfo, float* __restrict__ hbo,
    const u16* __restrict__ decinb, const u16* __restrict__ dwhib,
    const float* __restrict__ dbih, float* __restrict__ dgi)
{
    __shared__ __align__(16) char ldsu[EROWS * EKP * 2 + EROWS * 17 * 4];
    const int tid = threadIdx.x, wave = tid >> 6, lane = tid & 63;
    const int fr = lane & 15, kq = lane >> 4;

    if (blockIdx.x >= ENC_BLOCKS) {
        u16* As = (u16*)ldsu;
        u16* Bs = As + 64 * 40;
        const int tile = blockIdx.x - ENC_BLOCKS;
        const int m0 = (tile % DGI_TM) * 64, n0 = (tile / DGI_TM) * 64;
        const int wm = (wave >> 1) * 32, wn = (wave & 1) * 32;
        const int srow = tid >> 2, scol = (tid & 3) * 8;
        f32x4 acc[2][2];
#pragma unroll
        for (int i = 0; i < 2; ++i)
#pragma unroll
            for (int j = 0; j < 2; ++j) acc[i][j] = (f32x4){0.f, 0.f, 0.f, 0.f};

        for (int k0 = 0; k0 < H; k0 += 32) {
            {
                int gr = m0 + srow, gc = k0 + scol;
                bf16x8 v = (bf16x8){0,0,0,0,0,0,0,0};
                if (gr < MM && gc + 8 <= H) v = *(const bf16x8*)(decinb + (long long)gr * H + gc);
                *(bf16x8*)&As[srow * 40 + scol] = v;
            }
            {
                int gr = n0 + srow, gc = k0 + scol;
                bf16x8 v = (bf16x8){0,0,0,0,0,0,0,0};
                if (gr < H3 && gc + 8 <= H) v = *(const bf16x8*)(dwhib + (long long)gr * H + gc);
                *(bf16x8*)&Bs[srow * 40 + scol] = v;
            }
            __syncthreads();
            bf16x8 af[2], bfr[2];
#pragma unroll
            for (int i = 0; i < 2; ++i) af[i]  = *(const bf16x8*)&As[(wm + i * 16 + fr) * 40 + kq * 8];
#pragma unroll
            for (int j = 0; j < 2; ++j) bfr[j] = *(const bf16x8*)&Bs[(wn + j * 16 + fr) * 40 + kq * 8];
#pragma unroll
            for (int i = 0; i < 2; ++i)
#pragma unroll
                for (int j = 0; j < 2; ++j)
                    acc[i][j] = __builtin_amdgcn_mfma_f32_16x16x32_bf16(af[i], bfr[j], acc[i][j], 0, 0, 0);
            __syncthreads();
        }
#pragma unroll
        for (int i = 0; i < 2; ++i)
#pragma unroll
            for (int j = 0; j < 2; ++j) {
                int col = n0 + wn + j * 16 + fr;
                float bv = (col < H3) ? dbih[col] : 0.f;
#pragma unroll
                for (int r = 0; r < 4; ++r) {
                    int row = m0 + wm + i * 16 + kq * 4 + r;
                    if (row < MM && col < H3) dgi[(long long)row * H3 + col] = acc[i][j][r] + bv;
                }
            }
        return;
    }

    u16* wlds = (u16*)ldsu;
    float* ghs = (float*)(ldsu + EROWS * EKP * 2);
    const int bid = blockIdx.x;
    const int dir = bid / ENBLK, j = bid % ENBLK;
    const float* bhh = dir ? bhhb : bhhf;
    const float* gi  = dir ? gib  : gif;
    float* ys = dir ? ysb : ysf;
    float* ho = dir ? hbo : hfo;

    const u16* wsrc = wencp + (long long)(dir * ENBLK + j) * EROWS * EKP;
    for (int i = tid * 8; i < EROWS * EKP; i += 256 * 8)
        *(bf16x8*)&wlds[i] = *(const bf16x8*)&wsrc[i];
    for (int i = tid; i < EROWS * 17; i += 256) ghs[i] = 0.f;

    const int p0 = tid, p1 = 256 + tid;
    const bool has1 = (tid < 64);
    const int b0 = p0 / ESL, kl0 = p0 % ESL;
    const int b1 = has1 ? p1 / ESL : 0, kl1 = has1 ? p1 % ESL : 0;
    const int k0 = j * ESL;
    const int len0 = lens[b0];
    const int len1 = has1 ? lens[b1] : 0;
    const float bhr0 = bhh[k0 + kl0], bhz0 = bhh[H + k0 + kl0], bhn0 = bhh[2 * H + k0 + kl0];
    const float bhr1 = has1 ? bhh[k0 + kl1] : 0.f;
    const float bhz1 = has1 ? bhh[H + k0 + kl1] : 0.f;
    const float bhn1 = has1 ? bhh[2 * H + k0 + kl1] : 0.f;
    float h0r = 0.f, h1r = 0.f;

    unsigned* hb_d = hbuf + (long long)dir * S * B * EKP;
    int* flg_d = flags + dir * S * ENBLK;
    const u16* arow = &wlds[(wave * 16 + fr) * EKP + kq * 8];
    __syncthreads();

    for (int t = 0; t < S; ++t) {
        const int s = dir ? (S - 1 - t) : t;
        const float* gbase = gi + (long long)s * B * H3;
        float gr0 = gbase[b0 * H3 + k0 + kl0];
        float gz0 = gbase[b0 * H3 + H + k0 + kl0];
        float gn0 = gbase[b0 * H3 + 2 * H + k0 + kl0];
        float gr1 = 0.f, gz1 = 0.f, gn1 = 0.f;
        if (has1) {
            gr1 = gbase[b1 * H3 + k0 + kl1];
            gz1 = gbase[b1 * H3 + H + k0 + kl1];
            gn1 = gbase[b1 * H3 + 2 * H + k0 + kl1];
        }

        f32x4 acc = (f32x4){0.f, 0.f, 0.f, 0.f};
        if (t > 0) {
            const int* fl = flg_d + (t - 1) * ENBLK;
            for (;;) {
                int v = 1;
                if (lane < ENBLK)
                    v = __hip_atomic_load(&fl[lane], __ATOMIC_RELAXED,
                                          __HIP_MEMORY_SCOPE_AGENT);
                if (__all(v != 0)) break;
                __builtin_amdgcn_s_sleep(2);
            }
            asm volatile("" ::: "memory");
            const unsigned* hrow = hb_d + ((long long)(t - 1) * B + fr) * EKP + kq * 8;
            f32x4 acch = (f32x4){0.f, 0.f, 0.f, 0.f};
            f32x4 accl = (f32x4){0.f, 0.f, 0.f, 0.f};
#pragma unroll
            for (int kk = 0; kk < 13; ++kk) {
                u32x4 a = *(const u32x4*)(hrow + kk * 32);
                u32x4 b = *(const u32x4*)(hrow + kk * 32 + 4);
                union { unsigned u[4]; bf16x8 v; } hi, lo;
                hi.u[0] = __builtin_amdgcn_perm(a[1], a[0], 0x05040100u);
                hi.u[1] = __builtin_amdgcn_perm(a[3], a[2], 0x05040100u);
                hi.u[2] = __builtin_amdgcn_perm(b[1], b[0], 0x05040100u);
                hi.u[3] = __builtin_amdgcn_perm(b[3], b[2], 0x05040100u);
                lo.u[0] = __builtin_amdgcn_perm(a[1], a[0], 0x07060302u);
                lo.u[1] = __builtin_amdgcn_perm(a[3], a[2], 0x07060302u);
                lo.u[2] = __builtin_amdgcn_perm(b[1], b[0], 0x07060302u);
                lo.u[3] = __builtin_amdgcn_perm(b[3], b[2], 0x07060302u);
                bf16x8 av = *(const bf16x8*)(arow + kk * 32);
                acch = __builtin_amdgcn_mfma_f32_16x16x32_bf16(av, hi.v, acch, 0, 0, 0);
                accl = __builtin_amdgcn_mfma_f32_16x16x32_bf16(av, lo.v, accl, 0, 0, 0);
            }
            acc = acch + accl;
        }
#pragma unroll
        for (int r = 0; r < 4; ++r) ghs[(wave * 16 + kq * 4 + r) * 17 + fr] = acc[r];
        __syncthreads();

        unsigned* hpub = hb_d + (long long)t * B * EKP;
        {
            float ghr = ghs[kl0 * 17 + b0];
            float ghz = ghs[(ESL + kl0) * 17 + b0];
            float ghn = ghs[(2 * ESL + kl0) * 17 + b0];
            float rg = sigm(gr0 + ghr + bhr0);
            float zg = sigm(gz0 + ghz + bhz0);
            float ng = tanhf(gn0 + rg * (ghn + bhn0));
            float hn = (1.f - zg) * ng + zg * h0r;
            bool msk = s < len0;
            float y = msk ? hn : 0.f;
            if (msk) h0r = hn;
            ys[((long long)(b0 * S + s)) * H + k0 + kl0] = y;
            u16 hi = f2bf(h0r);
            unsigned packed = (unsigned)hi | ((unsigned)f2bf(h0r - bf2f(hi)) << 16);
            __hip_atomic_store(&hpub[b0 * EKP + k0 + kl0], packed, __ATOMIC_RELAXED,
                               __HIP_MEMORY_SCOPE_AGENT);
        }
        if (has1) {
            float ghr = ghs[kl1 * 17 + b1];
            float ghz = ghs[(ESL + kl1) * 17 + b1];
            float ghn = ghs[(2 * ESL + kl1) * 17 + b1];
            float rg = sigm(gr1 + ghr + bhr1);
            float zg = sigm(gz1 + ghz + bhz1);
            float ng = tanhf(gn1 + rg * (ghn + bhn1));
            float hn = (1.f - zg) * ng + zg * h1r;
            bool msk = s < len1;
            float y = msk ? hn : 0.f;
            if (msk) h1r = hn;
            ys[((long long)(b1 * S + s)) * H + k0 + kl1] = y;
            u16 hi = f2bf(h1r);
            unsigned packed = (unsigned)hi | ((unsigned)f2bf(h1r - bf2f(hi)) << 16);
            __hip_atomic_store(&hpub[b1 * EKP + k0 + kl1], packed, __ATOMIC_RELAXED,
                               __HIP_MEMORY_SCOPE_AGENT);
        }
        __syncthreads();
        if (tid == 0)
            __hip_atomic_store(&flg_d[t * ENBLK + j], 1, __ATOMIC_RELAXED,
                               __HIP_MEMORY_SCOPE_AGENT);
    }
    ho[b0 * H + k0 + kl0] = h0r;
    if (has1) ho[b1 * H + k0 + kl1] = h1r;
}

// packE + h0 merged: blocks 0..127 = packE tiles, 128..607 = h0 rows
__global__ __launch_bounds__(256) void packE_h0_kernel(
    const float* __restrict__ ysf, const float* __restrict__ ysb,
    u16* __restrict__ E, u16* __restrict__ ET,
    const float* __restrict__ hf, const float* __restrict__ hb,
    float* __restrict__ hf32, u16* __restrict__ hnk)
{
    __shared__ u16 tile[32][400];
    const int blk = blockIdx.x;
    if (blk < B * (S / 32)) {
        const int b = blk / (S / 32), s0 = (blk % (S / 32)) * 32;
        for (int si = 0; si < 32; ++si) {
            const long long base = ((long long)b * S + s0 + si) * H;
            for (int k = threadIdx.x; k < H; k += blockDim.x) {
                u16 v = f2bf(ysf[base + k] + ysb[base + k]);
                E[base + k] = v;
                tile[si][k] = v;
            }
        }
        __syncthreads();
        for (int idx = threadIdx.x; idx < 32 * H; idx += blockDim.x) {
            int k = idx >> 5, si = idx & 31;
            ET[((long long)b * H + k) * S + s0 + si] = tile[si][k];
        }
    } else {
        int n = blk - B * (S / 32), b = n & 15;
        for (int k = threadIdx.x; k < H; k += blockDim.x) {
            float v = hf[b * H + k] + hb[b * H + k];
            hf32[(long long)n * H + k] = v;
            hnk[(long long)n * H + k] = f2bf(v);
        }
    }
}

// ---------------------------------------------------------------------------
// A_t: GRU cell only. (R15 version)
// ---------------------------------------------------------------------------
__global__ __launch_bounds__(256) void gru_cell_kernel(
    const float* __restrict__ dgi, const float* __restrict__ dgh,
    float* __restrict__ hf32, u16* __restrict__ hall, int t)
{
    const int total = NB * H;
    for (int i = blockIdx.x * 256 + threadIdx.x; i < total; i += gridDim.x * 256) {
        int n = i / H, k = i % H;
        const float* gi = dgi + ((long long)t * NB + n) * H3;
        const float* gh = dgh + (long long)n * H3;
        float r  = sigm(gi[k] + gh[k]);
        float z  = sigm(gi[H + k] + gh[H + k]);
        float nn = tanhf(gi[2 * H + k] + r * gh[2 * H + k]);
        float h  = hf32[i];
        float hn = (1.f - z) * nn + z * h;
        hf32[i] = hn;
        hall[((long long)t * NB + n) * H + k] = f2bf(hn);
    }
}

// ---------------------------------------------------------------------------
// B_t: blocks 0..151 = dgh GEMM tiles for step t+1 (plain stores, consumed
// across the dispatch boundary); blocks 152..167 = attention for step t.
// (R15 version)
// ---------------------------------------------------------------------------
__global__ __launch_bounds__(512) void dec_attn_kernel(
    const u16* __restrict__ hall, const u16* __restrict__ dwhhb,
    const float* __restrict__ dbhh, float* __restrict__ dgh,
    const u16* __restrict__ decinb,
    const u16* __restrict__ Eb, const u16* __restrict__ ETb,
    const int* __restrict__ lens,
    const float* __restrict__ Wr, const float* __restrict__ br,
    const float* __restrict__ Wg, const float* __restrict__ bg,
    float* __restrict__ probfT, float* __restrict__ swvT,
    float* __restrict__ gout, int t)
{
    extern __shared__ char smem[];
    const int tid = threadIdx.x, wave = tid >> 6, lane = tid & 63;
    const int fr = lane & 15, kq = lane >> 4;
    const u16* hcur = hall + (long long)t * NB * H;

    if (blockIdx.x < DGH_TILES) {
        if (t == T - 1) return;            // no step t+1
        u16* As = (u16*)smem;              // [64][40]
        u16* Bs = As + 64 * 40;            // [64][40]
        const int tile = blockIdx.x;
        const int m0 = (tile % DGH_TM) * 64, n0 = (tile / DGH_TM) * 64;
        const bool act = (wave < 4);
        const int wm = (wave >> 1) * 32, wn = (wave & 1) * 32;
        const int srow = tid >> 2, scol = (tid & 3) * 8;
        f32x4 acc[2][2];
#pragma unroll
        for (int i = 0; i < 2; ++i)
#pragma unroll
            for (int j = 0; j < 2; ++j) acc[i][j] = (f32x4){0.f, 0.f, 0.f, 0.f};

        for (int k0 = 0; k0 < H; k0 += 32) {
            if (tid < 256) {
                {
                    int gr = m0 + srow, gc = k0 + scol;
                    bf16x8 v = (bf16x8){0,0,0,0,0,0,0,0};
                    if (gr < NB && gc + 8 <= H) v = *(const bf16x8*)(hcur + (long long)gr * H + gc);
                    *(bf16x8*)&As[srow * 40 + scol] = v;
                }
                {
                    int gr = n0 + srow, gc = k0 + scol;
                    bf16x8 v = (bf16x8){0,0,0,0,0,0,0,0};
                    if (gr < H3 && gc + 8 <= H) v = *(const bf16x8*)(dwhhb + (long long)gr * H + gc);
                    *(bf16x8*)&Bs[srow * 40 + scol] = v;
                }
            }
            __syncthreads();
            if (act) {
                bf16x8 af[2], bfr[2];
#pragma unroll
                for (int i = 0; i < 2; ++i) af[i]  = *(const bf16x8*)&As[(wm + i * 16 + fr) * 40 + kq * 8];
#pragma unroll
                for (int j = 0; j < 2; ++j) bfr[j] = *(const bf16x8*)&Bs[(wn + j * 16 + fr) * 40 + kq * 8];
#pragma unroll
                for (int i = 0; i < 2; ++i)
#pragma unroll
                    for (int j = 0; j < 2; ++j)
                        acc[i][j] = __builtin_amdgcn_mfma_f32_16x16x32_bf16(af[i], bfr[j], acc[i][j], 0, 0, 0);
            }
            __syncthreads();
        }
        if (act) {
#pragma unroll
            for (int i = 0; i < 2; ++i)
#pragma unroll
                for (int j = 0; j < 2; ++j) {
                    int col = n0 + wn + j * 16 + fr;
                    float bv = (col < H3) ? dbhh[col] : 0.f;
#pragma unroll
                    for (int r = 0; r < 4; ++r) {
                        int row = m0 + wm + i * 16 + kq * 4 + r;
                        if (row < NB && col < H3)
                            dgh[(long long)row * H3 + col] = acc[i][j][r] + bv;
                    }
                }
        }
        return;
    }

    // -------------------- attention role --------------------
    u16*   hls = (u16*)smem;                                   // [32][HP2]
    float* scs = (float*)(smem + 32 * HP2 * 2);                // [32][SCP]
    u16*   pls = (u16*)(smem + 32 * HP2 * 2 + 32 * SCP * 4);   // [32][PP]
    float* cxs = (float*)(smem + 32 * HP2 * 2 + 32 * SCP * 4 + 32 * PP * 2); // [32][CXP]

    const int b = blockIdx.x - DGH_TILES;
    const int len = lens[b];

    for (int i = tid; i < 32 * (HP2 - H); i += 512) {
        int r = i / (HP2 - H), c = H + i % (HP2 - H);
        hls[r * HP2 + c] = 0;
    }
    for (int i = tid; i < 2 * HP2; i += 512) hls[30 * HP2 + i] = 0;
    for (int i = tid; i < 2 * PP; i += 512) pls[30 * PP + i] = 0;

    for (int i = tid; i < 30 * H; i += 512) {
        int slot = i / H, k = i % H;
        hls[slot * HP2 + k] = hcur[((long long)(slot * 16 + b)) * H + k];
    }
    __syncthreads();

    // P1: scores
    {
        const int nt0 = wave * 2;
        f32x4 acc[2][2];
#pragma unroll
        for (int i = 0; i < 2; ++i)
#pragma unroll
            for (int jj = 0; jj < 2; ++jj) acc[i][jj] = (f32x4){0.f, 0.f, 0.f, 0.f};
        const u16* br0 = Eb + ((long long)b * S + nt0 * 16 + fr) * H + kq * 8;
        const u16* br1 = Eb + ((long long)b * S + (nt0 + 1) * 16 + fr) * H + kq * 8;
        const u16* ar0 = hls + fr * HP2 + kq * 8;
        const u16* ar1 = hls + (16 + fr) * HP2 + kq * 8;
#pragma unroll
        for (int kk = 0; kk < 13; ++kk) {
            bf16x8 av0 = *(const bf16x8*)(ar0 + kk * 32);
            bf16x8 av1 = *(const bf16x8*)(ar1 + kk * 32);
            bf16x8 bv0, bv1;
            if (kk == 12 && kq >= 2) {
                bv0 = (bf16x8){0,0,0,0,0,0,0,0}; bv1 = bv0;
            } else {
                bv0 = *(const bf16x8*)(br0 + kk * 32);
                bv1 = *(const bf16x8*)(br1 + kk * 32);
            }
            acc[0][0] = __builtin_amdgcn_mfma_f32_16x16x32_bf16(av0, bv0, acc[0][0], 0, 0, 0);
            acc[1][0] = __builtin_amdgcn_mfma_f32_16x16x32_bf16(av1, bv0, acc[1][0], 0, 0, 0);
            acc[0][1] = __builtin_amdgcn_mfma_f32_16x16x32_bf16(av0, bv1, acc[0][1], 0, 0, 0);
            acc[1][1] = __builtin_amdgcn_mfma_f32_16x16x32_bf16(av1, bv1, acc[1][1], 0, 0, 0);
        }
#pragma unroll
        for (int i = 0; i < 2; ++i)
#pragma unroll
            for (int jj = 0; jj < 2; ++jj)
#pragma unroll
                for (int r = 0; r < 4; ++r)
                    scs[(i * 16 + kq * 4 + r) * SCP + (nt0 + jj) * 16 + fr] = acc[i][jj][r];
    }
    __syncthreads();

    // P2: softmax
    for (int i = 0; i < 4; ++i) {
        int row = wave * 4 + i;
        if (row >= 30) break;
        int n = row * 16 + b;
        float v[4];
        float mx = -3.0e38f;
#pragma unroll
        for (int q = 0; q < 4; ++q) {
            int s = lane + 64 * q;
            float x = (s < len) ? scs[row * SCP + s] : -3.0e38f;
            v[q] = x; mx = fmaxf(mx, x);
        }
        mx = fmaxf(mx, __shfl_xor(mx, 1));  mx = fmaxf(mx, __shfl_xor(mx, 2));
        mx = fmaxf(mx, __shfl_xor(mx, 4));  mx = fmaxf(mx, __shfl_xor(mx, 8));
        mx = fmaxf(mx, __shfl_xor(mx, 16)); mx = fmaxf(mx, __shfl_xor(mx, 32));
        float sum = 0.f;
#pragma unroll
        for (int q = 0; q < 4; ++q) {
            int s = lane + 64 * q;
            float e = (s < len) ? __expf(v[q] - mx) : 0.f;
            v[q] = e; sum += e;
        }
        sum += __shfl_xor(sum, 1);  sum += __shfl_xor(sum, 2);
        sum += __shfl_xor(sum, 4);  sum += __shfl_xor(sum, 8);
        sum += __shfl_xor(sum, 16); sum += __shfl_xor(sum, 32);
        float inv = 1.f / sum;
#pragma unroll
        for (int q = 0; q < 4; ++q) {
            int s = lane + 64 * q;
            float pr = v[q] * inv;
            pls[row * PP + s] = f2bf(pr);
            probfT[((long long)(t * NB + n)) * S + s] = pr;
        }
    }
    __syncthreads();

    // P3: ctx
    for (int nt = wave; nt < 25; nt += 8) {
        f32x4 acc0 = (f32x4){0.f,0.f,0.f,0.f}, acc1 = (f32x4){0.f,0.f,0.f,0.f};
        const u16* brow = ETb + ((long long)b * H + nt * 16 + fr) * S + kq * 8;
        const u16* ar0 = pls + fr * PP + kq * 8;
        const u16* ar1 = pls + (16 + fr) * PP + kq * 8;
#pragma unroll
        for (int kk = 0; kk < 8; ++kk) {
            bf16x8 bv  = *(const bf16x8*)(brow + kk * 32);
            bf16x8 av0 = *(const bf16x8*)(ar0 + kk * 32);
            bf16x8 av1 = *(const bf16x8*)(ar1 + kk * 32);
            acc0 = __builtin_amdgcn_mfma_f32_16x16x32_bf16(av0, bv, acc0, 0, 0, 0);
            acc1 = __builtin_amdgcn_mfma_f32_16x16x32_bf16(av1, bv, acc1, 0, 0, 0);
        }
#pragma unroll
        for (int r = 0; r < 4; ++r) {
            cxs[(kq * 4 + r) * CXP + nt * 16 + fr] = acc0[r];
            cxs[(16 + kq * 4 + r) * CXP + nt * 16 + fr] = acc1[r];
        }
    }
    __syncthreads();

    // P4: p_gen (+ gate at t==0)
    for (int i = 0; i < 4; ++i) {
        int slot = wave + 8 * i;
        if (slot >= 30) break;
        int n = slot * 16 + b;
        const u16* xrow = decinb + ((long long)t * NB + n) * H;
        float p = 0.f;
        for (int k = lane; k < H; k += 64)
            p += bf2f(hls[slot * HP2 + k]) * Wr[k]
               + cxs[slot * CXP + k] * Wr[H + k]
               + bf2f(xrow[k]) * Wr[2 * H + k];
        p += __shfl_xor(p, 1);  p += __shfl_xor(p, 2);
        p += __shfl_xor(p, 4);  p += __shfl_xor(p, 8);
        p += __shfl_xor(p, 16); p += __shfl_xor(p, 32);
        if (lane == 0) swvT[t * NB + n] = sigm(p + br[0]);
        if (t == 0) {
            for (int g = 0; g < G; ++g) {
                float q = 0.f;
                for (int k = lane; k < H; k += 64)
                    q += cxs[slot * CXP + k] * Wg[g * H + k];
                q += __shfl_xor(q, 1);  q += __shfl_xor(q, 2);
                q += __shfl_xor(q, 4);  q += __shfl_xor(q, 8);
                q += __shfl_xor(q, 16); q += __shfl_xor(q, 32);
                if (lane == 0) gout[(long long)n * G + g] = q + bg[g];
            }
        }
    }
}

__global__ void scatter_all_kernel(float* __restrict__ out, const int* __restrict__ story,
                                   const int* __restrict__ lens, const float* __restrict__ swvT,
                                   const float* __restrict__ probfT) {
    const int n = blockIdx.x, t = blockIdx.y, b = n & 15, s = threadIdx.x;
    if (s < lens[b]) {
        int tok = story[b * S + s];
        atomicAdd(out + ((long long)n * T + t) * V + tok,
                  (1.f - swvT[t * NB + n]) * probfT[((long long)(t * NB + n)) * S + s]);
    }
}

// ---------------------------------------------------------------------------
extern "C" void kernel_launch(void* const* d_in, const int* in_sizes, int n_in,
                              void* d_out, int out_size, void* d_ws, size_t ws_size,
                              hipStream_t stream) {
    const int*   story = (const int*)d_in[0];
    const int*   lens  = (const int*)d_in[1];
    const int*   tgt   = (const int*)d_in[2];
    const int*   dom   = (const int*)d_in[3];
    const int*   sidx  = (const int*)d_in[4];
    const float* emb   = (const float*)d_in[5];
    const float* wihf  = (const float*)d_in[6];
    const float* whhf  = (const float*)d_in[7];
    const float* bihf  = (const float*)d_in[8];
    const float* bhhf  = (const float*)d_in[9];
    const float* wihb  = (const float*)d_in[10];
    const float* whhb  = (const float*)d_in[11];
    const float* bihb  = (const float*)d_in[12];
    const float* bhhb  = (const float*)d_in[13];
    const float* dwih  = (const float*)d_in[14];
    const float* dwhh  = (const float*)d_in[15];
    const float* dbih  = (const float*)d_in[16];
    const float* dbhh  = (const float*)d_in[17];
    const float* Wr    = (const float*)d_in[18];
    const float* br    = (const float*)d_in[19];
    const float* Wg    = (const float*)d_in[20];
    const float* bg    = (const float*)d_in[21];
    const float* slt   = (const float*)d_in[22];
    float* out = (float*)d_out;

    char* wsb = (char*)d_ws;
    size_t off = 0;
    auto alloc = [&](size_t bytes) -> char* {
        char* p = wsb + off;
        off += (bytes + 255) & ~(size_t)255;
        return p;
    };
    u16*   embb   = (u16*)alloc((size_t)V * H * 2);
    u16*   wihfb  = (u16*)alloc((size_t)H3 * H * 2);
    u16*   wihbb  = (u16*)alloc((size_t)H3 * H * 2);
    u16*   dwihb  = (u16*)alloc((size_t)H3 * H * 2);
    u16*   dwhhb  = (u16*)alloc((size_t)H3 * H * 2);
    u16*   wencp  = (u16*)alloc((size_t)2 * ENBLK * EROWS * EKP * 2);
    unsigned* hbuf = (unsigned*)alloc((size_t)2 * S * B * EKP * 4);
    int*   flags  = (int*)alloc((size_t)2 * S * ENBLK * 4);
    u16*   xb     = (u16*)alloc((size_t)S * B * H * 2);
    u16*   decinb = (u16*)alloc((size_t)T * NB * H * 2);
    float* gif    = (float*)alloc((size_t)S * B * H3 * 4);
    float* gib    = (float*)alloc((size_t)S * B * H3 * 4);
    float* dgi    = (float*)alloc((size_t)T * NB * H3 * 4);
    float* ysf    = (float*)alloc((size_t)B * S * H * 4);
    float* ysb    = (float*)alloc((size_t)B * S * H * 4);
    float* hfv    = (float*)alloc((size_t)B * H * 4);
    float* hbv    = (float*)alloc((size_t)B * H * 4);
    u16*   Eb     = (u16*)alloc((size_t)B * S * H * 2);
    u16*   ETb    = (u16*)alloc((size_t)B * H * S * 2);
    float* hf32   = (float*)alloc((size_t)NB * H * 4);
    u16*   hnk    = (u16*)alloc((size_t)NB * H * 2);
    u16*   hall   = (u16*)alloc((size_t)T * NB * H * 2);
    float* dgh    = (float*)alloc((size_t)NB * H3 * 4);
    float* probfT = (float*)alloc((size_t)T * NB * S * 4);
    float* swvT   = (float*)alloc((size_t)T * NB * 4);
    float* rowsumT = (float*)alloc((size_t)T * NB * 4);
    (void)ws_size; (void)in_sizes; (void)n_in; (void)out_size;

    hipFuncSetAttribute((const void*)dec_attn_kernel,
                        hipFuncAttributeMaxDynamicSharedMemorySize, FUSED_LDS);

    // ---- setup ------------------------------------------------------------
    hipMemsetAsync(flags, 0, (size_t)2 * S * ENBLK * 4, stream);
    hipMemsetAsync(hbuf, 0, (size_t)2 * S * B * EKP * 4, stream);
    hipMemsetAsync(rowsumT, 0, (size_t)T * NB * 4, stream);
    prep_all_kernel<<<2048, 256, 0, stream>>>(emb, embb, wihf, wihfb, wihb, wihbb,
                                              dwih, dwihb, dwhh, dwhhb,
                                              whhf, whhb, wencp);
    embed_decin_kernel<<<S * B + T * NB, 256, 0, stream>>>(
        story, embb, xb, tgt, dom, sidx, slt, decinb);
    {
        dim3 g((S * B + 63) / 64, (H3 + 63) / 64, 2);
        gemm_xw2_kernel<<<g, 256, 0, stream>>>(xb, wihfb, wihbb, bihf, bihb, gif, gib);
    }

    // ---- encoder recurrence + concurrent dgi GEMM -------------------------
    enc_dgi_kernel<<<ENC_BLOCKS + DGI_TILES, 256, 0, stream>>>(
        wencp, bhhf, bhhb, gif, gib, lens, hbuf, flags, ysf, ysb, hfv, hbv,
        decinb, dwihb, dbih, dgi);
    packE_h0_kernel<<<B * (S / 32) + NB, 256, 0, stream>>>(
        ysf, ysb, Eb, ETb, hfv, hbv, hf32, hnk);

    // ---- decoder: dgh_0 + per-step {cell, attn || next-dgh} ---------------
    {
        dim3 g((NB + 63) / 64, (H3 + 63) / 64);
        gemm_bt<<<g, 256, 0, stream>>>(hnk, dwhhb, dbhh, dgh, NB, H3, H, H, H, H3);
    }
    for (int t = 0; t < T; ++t) {
        gru_cell_kernel<<<750, 256, 0, stream>>>(dgi, dgh, hf32, hall, t);
        dec_attn_kernel<<<DGH_TILES + 16, 512, FUSED_LDS, stream>>>(
            hall, dwhhb, dbhh, dgh, decinb, Eb, ETb, lens,
            Wr, br, Wg, bg, probfT, swvT, out + (size_t)NB * T * V, t);
    }

    // ---- vocab projection: pass A (rowsum only) + pass B (fused scale) ----
    {
        dim3 g((MM + 127) / 128, (V + 127) / 128);
        vocab_rowsum_kernel<<<g, 256, 0, stream>>>(hall, embb, rowsumT);
        vocab_write_kernel<<<g, 256, 0, stream>>>(hall, embb, swvT, rowsumT, out);
    }
    { dim3 g(NB, T); scatter_all_kernel<<<g, 256, 0, stream>>>(out, story, lens, swvT, probfT); }
}